// Round 4
// baseline (93.480 us; speedup 1.0000x reference)
//
#include <hip/hip_runtime.h>
#include <hip/hip_bf16.h>
#include <hip/hip_fp16.h>

#define BB 4096
#define DD 512
#define LLAB 20
#define NN 8192
#define KK 64

constexpr float kNegInf = -1.0e9f;
constexpr float kLn2 = 0.69314718055994530942f;

// workspace layout (bytes)
#define OFF_STATS 16384
#define OFF_WL    16640
#define OFF_HLAB  33280
#define OFF_HAL   66048
#define OFF_IEH   131584
#define OFF_ALEH  (OFF_IEH + (size_t)BB * DD * 2)
#define WS_NEED   (OFF_ALEH + (size_t)NN * DD * 2)

typedef _Float16 h2_t __attribute__((ext_vector_type(2)));

__device__ __forceinline__ float dot4(const float4& a, const float4& b) {
  return a.x * b.x + a.y * b.y + a.z * b.z + a.w * b.w;
}

__device__ __forceinline__ float waveReduceSum(float v) {
#pragma unroll
  for (int s = 1; s < 64; s <<= 1) v += __shfl_xor(v, s);
  return v;
}

__device__ __forceinline__ float waveReduceMax(float v) {
#pragma unroll
  for (int s = 1; s < 64; s <<= 1) v = fmaxf(v, __shfl_xor(v, s));
  return v;
}

__device__ __forceinline__ float waveReduceMin(float v) {
#pragma unroll
  for (int s = 1; s < 64; s <<= 1) v = fminf(v, __shfl_xor(v, s));
  return v;
}

__device__ __forceinline__ unsigned pk_h(float a, float b) {
  return __builtin_bit_cast(unsigned, __builtin_amdgcn_cvt_pkrtz(a, b));
}

// f32 -> packed f16 table, 8 elements per thread.
__device__ __forceinline__ void cvt8h(const float* __restrict__ src,
                                      ushort* __restrict__ dst, int i) {
  const float4* s4 = (const float4*)src;
  float4 a = s4[2 * i], c = s4[2 * i + 1];
  uint4 o;
  o.x = pk_h(a.x, a.y);
  o.y = pk_h(a.z, a.w);
  o.z = pk_h(c.x, c.y);
  o.w = pk_h(c.z, c.w);
  ((uint4*)dst)[i] = o;
}

__device__ __forceinline__ unsigned long long hash20(const float* __restrict__ p) {
  unsigned long long h = 1469598103934665603ull;
#pragma unroll
  for (int t = 0; t < LLAB; ++t) {
    h ^= (unsigned long long)__float_as_uint(p[t]);
    h *= 1099511628211ull;
  }
  return h;
}

// 8-element f16x2-packed dot, f32 accumulate.
__device__ __forceinline__ float dot8h(const uint4& a, const uint4& q, float acc) {
#if __has_builtin(__builtin_amdgcn_fdot2)
  acc = __builtin_amdgcn_fdot2(__builtin_bit_cast(h2_t, a.x),
                               __builtin_bit_cast(h2_t, q.x), acc, false);
  acc = __builtin_amdgcn_fdot2(__builtin_bit_cast(h2_t, a.y),
                               __builtin_bit_cast(h2_t, q.y), acc, false);
  acc = __builtin_amdgcn_fdot2(__builtin_bit_cast(h2_t, a.z),
                               __builtin_bit_cast(h2_t, q.z), acc, false);
  acc = __builtin_amdgcn_fdot2(__builtin_bit_cast(h2_t, a.w),
                               __builtin_bit_cast(h2_t, q.w), acc, false);
  return acc;
#else
  const unsigned au[4] = {a.x, a.y, a.z, a.w};
  const unsigned qu[4] = {q.x, q.y, q.z, q.w};
#pragma unroll
  for (int t = 0; t < 4; ++t) {
    float2 fa = __half22float2(*reinterpret_cast<const __half2*>(&au[t]));
    float2 fq = __half22float2(*reinterpret_cast<const __half2*>(&qu[t]));
    acc += fa.x * fq.x + fa.y * fq.y;
  }
  return acc;
#endif
}

__global__ void init_kernel(unsigned* stats) {
  if (threadIdx.x == 0) {
    stats[0] = 0u;  // acc count
    stats[1] = 0u;  // worklist count
  }
}

// Fused prep: f16-convert both tables, hash both label tables, init stats.
__global__ __launch_bounds__(256) void prep_kernel(
    const float* __restrict__ ie, const float* __restrict__ ale,
    const float* __restrict__ labels, const float* __restrict__ al,
    ushort* __restrict__ ie_h, ushort* __restrict__ ale_h,
    unsigned long long* __restrict__ h_lab, unsigned long long* __restrict__ h_al,
    unsigned* __restrict__ stats) {
  const int i = blockIdx.x * 256 + threadIdx.x;
  if (i == 0) {
    stats[0] = 0u;
    stats[1] = 0u;
  }
  const int n8_ie = BB * DD / 8;
  if (i < n8_ie) {
    cvt8h(ie, ie_h, i);
  } else {
    cvt8h(ale, ale_h, i - n8_ie);
  }
  if (i < BB) {
    h_lab[i] = hash20(labels + (size_t)i * LLAB);
  } else if (i < BB + NN) {
    h_al[i - BB] = hash20(al + (size_t)(i - BB) * LLAB);
  }
}

// Main pass: one block (4 waves) per row; each wave owns 16 negatives.
// Depth-3 register prefetch pipeline over the two gather streams.
__global__ __launch_bounds__(256, 6) void row_f16_kernel(
    const float* __restrict__ ie, const float* __restrict__ le,
    const ushort* __restrict__ ie_h, const ushort* __restrict__ ale_h,
    const unsigned long long* __restrict__ h_lab,
    const unsigned long long* __restrict__ h_al,
    const int* __restrict__ nin, const int* __restrict__ nlb,
    float* __restrict__ per_ex, int* __restrict__ wl,
    unsigned* __restrict__ stats) {
  const int b = blockIdx.x;
  const int tid = threadIdx.x;
  const int lane = tid & 63;
  const int wave = tid >> 6;

  __shared__ float sims[1 + 4 * KK];
  __shared__ float wred[8];

  // Query fragments: elements lane*8 .. lane*8+7, f32 for sim_pos, f16-packed
  // for the negative dots.
  const float4* ie4 = (const float4*)(ie + (size_t)b * DD);
  const float4* le4 = (const float4*)(le + (size_t)b * DD);
  float4 qi0 = ie4[2 * lane], qi1 = ie4[2 * lane + 1];
  float4 ql0 = le4[2 * lane], ql1 = le4[2 * lane + 1];

  if (wave == 0) {
    float p = dot4(qi0, ql0) + dot4(qi1, ql1);
    p = waveReduceSum(p);
    if (lane == 0) sims[0] = p;
  }

  uint4 qih, qlh;
  qih.x = pk_h(qi0.x, qi0.y);
  qih.y = pk_h(qi0.z, qi0.w);
  qih.z = pk_h(qi1.x, qi1.y);
  qih.w = pk_h(qi1.z, qi1.w);
  qlh.x = pk_h(ql0.x, ql0.y);
  qlh.y = pk_h(ql0.z, ql0.w);
  qlh.z = pk_h(ql1.x, ql1.y);
  qlh.w = pk_h(ql1.z, ql1.w);

  const unsigned long long hb = h_lab[b];
  const int wuni = __builtin_amdgcn_readfirstlane(wave);
  const int base = b * KK + wuni * 16;

  // Rotating prefetch buffers (all indexing compile-time after full unroll).
  uint4 bufA[4], bufB[4];
  bool badl_q[4], badi_q[4];

#pragma unroll
  for (int p = 0; p < 3; ++p) {
    const int jl = nlb[base + p];  // uniform -> s_load
    const int ji = nin[base + p];
    bufA[p] = ((const uint4*)(ale_h + (size_t)jl * DD))[lane];
    bufB[p] = ((const uint4*)(ie_h + (size_t)ji * DD))[lane];
    badl_q[p] = (h_al[jl] == hb);
    badi_q[p] = (h_lab[ji] == hb);
  }

#pragma unroll
  for (int kk = 0; kk < 16; ++kk) {
    if (kk < 13) {
      const int t = kk + 3;
      const int jl = nlb[base + t];
      const int ji = nin[base + t];
      bufA[t & 3] = ((const uint4*)(ale_h + (size_t)jl * DD))[lane];
      bufB[t & 3] = ((const uint4*)(ie_h + (size_t)ji * DD))[lane];
      badl_q[t & 3] = (h_al[jl] == hb);
      badi_q[t & 3] = (h_lab[ji] == hb);
    }
    const uint4 A = bufA[kk & 3];  // ale row (f16x8)
    const uint4 Bv = bufB[kk & 3]; // ie row (f16x8)
    const bool bad_lb = badl_q[kk & 3];
    const bool bad_in = badi_q[kk & 3];

    float a_il = dot8h(A, qih, 0.0f);
    float a_ll = dot8h(A, qlh, 0.0f);
    float a_ii = dot8h(Bv, qih, 0.0f);
    float a_li = dot8h(Bv, qlh, 0.0f);

    // component-split butterfly; lane&3: 0->il, 1->ii, 2->ll, 3->li
    const bool oddl = (lane & 1) != 0;
    float sx = oddl ? a_il : a_ii;
    float sy = oddl ? a_ll : a_li;
    float rx = __shfl_xor(sx, 1);
    float ry = __shfl_xor(sy, 1);
    float mx = (oddl ? a_ii : a_il) + rx;
    float my = (oddl ? a_li : a_ll) + ry;
    const bool hi2 = (lane & 2) != 0;
    float s1 = hi2 ? mx : my;
    float r1 = __shfl_xor(s1, 2);
    float v = (hi2 ? my : mx) + r1;
    v += __shfl_xor(v, 4);
    v += __shfl_xor(v, 8);
    v += __shfl_xor(v, 16);
    v += __shfl_xor(v, 32);

    if (lane < 4) {
      const bool badf = (lane & 1) ? bad_in : bad_lb;
      const float s = badf ? v + kNegInf : v;
      const int slot = ((lane & 1) << 1) | ((lane >> 1) & 1);  // il0 ii2 ll1 li3
      sims[1 + slot * KK + wuni * 16 + kk] = s;
    }
  }
  __syncthreads();

  const float v = sims[1 + tid];
  const float s0 = sims[0];
  float wmax = waveReduceMax(v);
  if (lane == 0) wred[wave] = wmax;
  __syncthreads();
  float m = fmaxf(fmaxf(wred[0], wred[1]), fmaxf(wred[2], wred[3]));
  m = fmaxf(m, s0);
  const float e = expf(v - m);
  float wsum = waveReduceSum(e);
  if (lane == 0) wred[4 + wave] = wsum;
  __syncthreads();
  if (tid == 0) {
    const float tot = wred[4] + wred[5] + wred[6] + wred[7] + expf(s0 - m);
    const float pe = m + logf(tot) - s0;
    per_ex[b] = pe;
    const float max_il = wred[0];  // wave 0 reduced sims[1..64] = il negatives
    // Worklist: near the scale-branch threshold OR accuracy near-tie ->
    // exact f32 recompute (incl. acc) in fixup; else count acc here.
    const bool wl_row = (pe < 1.0f) || (fabsf(s0 - max_il) < 0.25f);
    if (wl_row) {
      const unsigned p = atomicAdd(&stats[1], 1u);
      wl[p] = b;
    } else if (s0 >= max_il) {
      atomicAdd(&stats[0], 1u);
    }
  }
}

// Exact f32 row compute (shared by fallback and fixup).
__device__ __forceinline__ void row_f32_body(
    int b, const float* __restrict__ ie, const float* __restrict__ le,
    const float* __restrict__ labels, const float* __restrict__ ale,
    const float* __restrict__ al, const int* __restrict__ nin,
    const int* __restrict__ nlb, float* __restrict__ per_ex,
    unsigned* __restrict__ stats, bool count_acc, float* sims, float* wred) {
  const int tid = threadIdx.x;
  const int lane = tid & 63;
  const int wave = tid >> 6;

  const float4* ie4 = (const float4*)(ie + (size_t)b * DD);
  const float4* le4 = (const float4*)(le + (size_t)b * DD);
  float4 ier0 = ie4[lane], ier1 = ie4[lane + 64];
  float4 ler0 = le4[lane], ler1 = le4[lane + 64];
  float lab = (lane < LLAB) ? labels[(size_t)b * LLAB + lane] : 0.0f;

  if (wave == 0) {
    float p = dot4(ier0, ler0) + dot4(ier1, ler1);
    p = waveReduceSum(p);
    if (lane == 0) sims[0] = p;
  }

#pragma unroll 2
  for (int kk = 0; kk < KK / 4; ++kk) {
    const int k = wave * (KK / 4) + kk;
    const int j_lb = __builtin_amdgcn_readfirstlane(nlb[(size_t)b * KK + k]);
    const int j_in = __builtin_amdgcn_readfirstlane(nin[(size_t)b * KK + k]);

    const float4* rle = (const float4*)(ale + (size_t)j_lb * DD);
    const float4* rie = (const float4*)(ie + (size_t)j_in * DD);
    float4 vle0 = rle[lane], vle1 = rle[lane + 64];
    float4 vie0 = rie[lane], vie1 = rie[lane + 64];

    bool ein = true, elb = true;
    if (lane < LLAB) {
      ein = (labels[(size_t)j_in * LLAB + lane] == lab);
      elb = (al[(size_t)j_lb * LLAB + lane] == lab);
    }
    const bool bad_in = (__ballot(ein) == ~0ull);
    const bool bad_lb = (__ballot(elb) == ~0ull);

    float a_il = dot4(vle0, ier0) + dot4(vle1, ier1);
    float a_ll = dot4(vle0, ler0) + dot4(vle1, ler1);
    float a_ii = dot4(vie0, ier0) + dot4(vie1, ier1);
    float a_li = dot4(vie0, ler0) + dot4(vie1, ler1);

    const bool oddl = (lane & 1) != 0;
    float sx = oddl ? a_il : a_ii;
    float sy = oddl ? a_ll : a_li;
    float rx = __shfl_xor(sx, 1);
    float ry = __shfl_xor(sy, 1);
    float mx = (oddl ? a_ii : a_il) + rx;
    float my = (oddl ? a_li : a_ll) + ry;
    const bool hi2 = (lane & 2) != 0;
    float s1 = hi2 ? mx : my;
    float r1 = __shfl_xor(s1, 2);
    float v = (hi2 ? my : mx) + r1;
    v += __shfl_xor(v, 4);
    v += __shfl_xor(v, 8);
    v += __shfl_xor(v, 16);
    v += __shfl_xor(v, 32);

    if (lane < 4) {
      const bool badf = (lane & 1) ? bad_in : bad_lb;
      const float s = badf ? v + kNegInf : v;
      const int slot = ((lane & 1) << 1) | ((lane >> 1) & 1);
      sims[1 + slot * KK + k] = s;
    }
  }
  __syncthreads();

  const float v = sims[1 + tid];
  const float s0 = sims[0];
  float wmax = waveReduceMax(v);
  if (lane == 0) wred[wave] = wmax;
  __syncthreads();
  float m = fmaxf(fmaxf(wred[0], wred[1]), fmaxf(wred[2], wred[3]));
  m = fmaxf(m, s0);
  const float e = expf(v - m);
  float wsum = waveReduceSum(e);
  if (lane == 0) wred[4 + wave] = wsum;
  __syncthreads();
  if (tid == 0) {
    const float tot = wred[4] + wred[5] + wred[6] + wred[7] + expf(s0 - m);
    per_ex[b] = m + logf(tot) - s0;
    if (count_acc) {
      const float max_il = wred[0];
      if (s0 >= max_il) atomicAdd(&stats[0], 1u);
    }
  }
}

// Fallback: full exact pass (used only if ws too small).
__global__ __launch_bounds__(256) void row_f32_kernel(
    const float* __restrict__ ie, const float* __restrict__ le,
    const float* __restrict__ labels, const float* __restrict__ ale,
    const float* __restrict__ al, const int* __restrict__ nin,
    const int* __restrict__ nlb, float* __restrict__ per_ex,
    unsigned* __restrict__ stats) {
  __shared__ float sims[1 + 4 * KK];
  __shared__ float wred[8];
  row_f32_body(blockIdx.x, ie, le, labels, ale, al, nin, nlb, per_ex, stats,
               true, sims, wred);
}

// Fixup: exact recompute (per_ex AND acc) of worklist rows.
__global__ __launch_bounds__(256) void fixup_kernel(
    const float* __restrict__ ie, const float* __restrict__ le,
    const float* __restrict__ labels, const float* __restrict__ ale,
    const float* __restrict__ al, const int* __restrict__ nin,
    const int* __restrict__ nlb, float* __restrict__ per_ex,
    const int* __restrict__ wl, unsigned* __restrict__ stats) {
  __shared__ float sims[1 + 4 * KK];
  __shared__ float wred[8];
  const int n = (int)stats[1];
  for (int w = blockIdx.x; w < n; w += gridDim.x) {
    row_f32_body(wl[w], ie, le, labels, ale, al, nin, nlb, per_ex, stats,
                 true, sims, wred);
    __syncthreads();
  }
}

__global__ __launch_bounds__(256) void finalize_kernel(
    const float* __restrict__ per_ex, const unsigned* __restrict__ stats,
    float* __restrict__ out) {
  __shared__ float wred[8];
  const int tid = threadIdx.x;
  const int lane = tid & 63;
  const int wave = tid >> 6;

  float mn = 1.0e30f;
  for (int i = tid; i < BB; i += 256) mn = fminf(mn, per_ex[i]);
  mn = waveReduceMin(mn);
  if (lane == 0) wred[wave] = mn;
  __syncthreads();
  const float minpe = fminf(fminf(wred[0], wred[1]), fminf(wred[2], wred[3]));
  const bool scale_on = (minpe < kLn2);  // max(q) > 0.5
  __syncthreads();

  float sum = 0.0f;
  for (int i = tid; i < BB; i += 256) {
    const float pe = per_ex[i];
    float s = 1.0f;
    if (scale_on) {
      const float q = expf(-pe);
      const float t = 2.0f * (1.0f - q);
      const float t2 = t * t;
      s = t2 * t2;
    }
    sum += pe * s;
  }
  sum = waveReduceSum(sum);
  if (lane == 0) wred[4 + wave] = sum;
  __syncthreads();
  if (tid == 0) {
    const float tot = wred[4] + wred[5] + wred[6] + wred[7];
    out[0] = tot / (float)BB;
    out[1] = (float)stats[0] / (float)BB;
  }
}

extern "C" void kernel_launch(void* const* d_in, const int* in_sizes, int n_in,
                              void* d_out, int out_size, void* d_ws, size_t ws_size,
                              hipStream_t stream) {
  const float* ie = (const float*)d_in[0];
  const float* le = (const float*)d_in[1];
  const float* labels = (const float*)d_in[2];
  const float* ale = (const float*)d_in[3];
  const float* al = (const float*)d_in[4];
  const int* nin = (const int*)d_in[5];
  const int* nlb = (const int*)d_in[6];
  float* out = (float*)d_out;

  float* per_ex = (float*)d_ws;
  unsigned* stats = (unsigned*)((char*)d_ws + OFF_STATS);
  int* wl = (int*)((char*)d_ws + OFF_WL);

  if (ws_size >= WS_NEED) {
    ushort* ie_h = (ushort*)((char*)d_ws + OFF_IEH);
    ushort* ale_h = (ushort*)((char*)d_ws + OFF_ALEH);
    unsigned long long* h_lab = (unsigned long long*)((char*)d_ws + OFF_HLAB);
    unsigned long long* h_al = (unsigned long long*)((char*)d_ws + OFF_HAL);
    const int prep_blocks = (BB * DD / 8 + NN * DD / 8) / 256;
    hipLaunchKernelGGL(prep_kernel, dim3(prep_blocks), dim3(256), 0, stream,
                       ie, ale, labels, al, ie_h, ale_h, h_lab, h_al, stats);
    hipLaunchKernelGGL(row_f16_kernel, dim3(BB), dim3(256), 0, stream,
                       ie, le, ie_h, ale_h, h_lab, h_al, nin, nlb, per_ex, wl, stats);
    hipLaunchKernelGGL(fixup_kernel, dim3(128), dim3(256), 0, stream,
                       ie, le, labels, ale, al, nin, nlb, per_ex, wl, stats);
  } else {
    hipLaunchKernelGGL(init_kernel, dim3(1), dim3(64), 0, stream, stats);
    hipLaunchKernelGGL(row_f32_kernel, dim3(BB), dim3(256), 0, stream,
                       ie, le, labels, ale, al, nin, nlb, per_ex, stats);
  }
  hipLaunchKernelGGL(finalize_kernel, dim3(1), dim3(256), 0, stream,
                     per_ex, stats, out);
}

// Round 5
// 90.005 us; speedup vs baseline: 1.0386x; 1.0386x over previous
//
#include <hip/hip_runtime.h>
#include <hip/hip_bf16.h>
#include <hip/hip_fp16.h>

#define BB 4096
#define DD 512
#define LLAB 20
#define NN 8192
#define KK 64

constexpr float kNegInf = -1.0e9f;
constexpr float kLn2 = 0.69314718055994530942f;

// workspace layout (bytes)
#define OFF_STATS 16384
#define OFF_WL    16640
#define OFF_HLAB  33280
#define OFF_HAL   66048
#define OFF_IEH   131584
#define OFF_ALEH  (OFF_IEH + (size_t)BB * DD * 2)
#define WS_NEED   (OFF_ALEH + (size_t)NN * DD * 2)

typedef _Float16 h2_t __attribute__((ext_vector_type(2)));

__device__ __forceinline__ float dot4(const float4& a, const float4& b) {
  return a.x * b.x + a.y * b.y + a.z * b.z + a.w * b.w;
}

__device__ __forceinline__ float waveReduceSum(float v) {
#pragma unroll
  for (int s = 1; s < 64; s <<= 1) v += __shfl_xor(v, s);
  return v;
}

__device__ __forceinline__ float waveReduceMax(float v) {
#pragma unroll
  for (int s = 1; s < 64; s <<= 1) v = fmaxf(v, __shfl_xor(v, s));
  return v;
}

__device__ __forceinline__ float waveReduceMin(float v) {
#pragma unroll
  for (int s = 1; s < 64; s <<= 1) v = fminf(v, __shfl_xor(v, s));
  return v;
}

__device__ __forceinline__ unsigned pk_h(float a, float b) {
  return __builtin_bit_cast(unsigned, __builtin_amdgcn_cvt_pkrtz(a, b));
}

// f32 -> packed f16 table, 8 elements per thread.
__device__ __forceinline__ void cvt8h(const float* __restrict__ src,
                                      ushort* __restrict__ dst, int i) {
  const float4* s4 = (const float4*)src;
  float4 a = s4[2 * i], c = s4[2 * i + 1];
  uint4 o;
  o.x = pk_h(a.x, a.y);
  o.y = pk_h(a.z, a.w);
  o.z = pk_h(c.x, c.y);
  o.w = pk_h(c.z, c.w);
  ((uint4*)dst)[i] = o;
}

__device__ __forceinline__ unsigned long long hash20(const float* __restrict__ p) {
  unsigned long long h = 1469598103934665603ull;
#pragma unroll
  for (int t = 0; t < LLAB; ++t) {
    h ^= (unsigned long long)__float_as_uint(p[t]);
    h *= 1099511628211ull;
  }
  return h;
}

// 8-element f16x2-packed dot, f32 accumulate.
__device__ __forceinline__ float dot8h(const uint4& a, const uint4& q, float acc) {
#if __has_builtin(__builtin_amdgcn_fdot2)
  acc = __builtin_amdgcn_fdot2(__builtin_bit_cast(h2_t, a.x),
                               __builtin_bit_cast(h2_t, q.x), acc, false);
  acc = __builtin_amdgcn_fdot2(__builtin_bit_cast(h2_t, a.y),
                               __builtin_bit_cast(h2_t, q.y), acc, false);
  acc = __builtin_amdgcn_fdot2(__builtin_bit_cast(h2_t, a.z),
                               __builtin_bit_cast(h2_t, q.z), acc, false);
  acc = __builtin_amdgcn_fdot2(__builtin_bit_cast(h2_t, a.w),
                               __builtin_bit_cast(h2_t, q.w), acc, false);
  return acc;
#else
  const unsigned au[4] = {a.x, a.y, a.z, a.w};
  const unsigned qu[4] = {q.x, q.y, q.z, q.w};
#pragma unroll
  for (int t = 0; t < 4; ++t) {
    float2 fa = __half22float2(*reinterpret_cast<const __half2*>(&au[t]));
    float2 fq = __half22float2(*reinterpret_cast<const __half2*>(&qu[t]));
    acc += fa.x * fq.x + fa.y * fq.y;
  }
  return acc;
#endif
}

__device__ __forceinline__ uint4 ld_row(const ushort* __restrict__ tab, int j, int lane) {
  return ((const uint4*)(tab + (size_t)j * DD))[lane];
}

// One k-step: 4 dots, component-split butterfly, masked store of 4 sims.
__device__ __forceinline__ void compute_k(const uint4& A, const uint4& Bv,
                                          bool bad_lb, bool bad_in,
                                          const uint4& qih, const uint4& qlh,
                                          int lane, float* sims, int k) {
  float a_il = dot8h(A, qih, 0.0f);
  float a_ll = dot8h(A, qlh, 0.0f);
  float a_ii = dot8h(Bv, qih, 0.0f);
  float a_li = dot8h(Bv, qlh, 0.0f);

  // component-split butterfly; lane&3: 0->il, 1->ii, 2->ll, 3->li
  const bool oddl = (lane & 1) != 0;
  float sx = oddl ? a_il : a_ii;
  float sy = oddl ? a_ll : a_li;
  float rx = __shfl_xor(sx, 1);
  float ry = __shfl_xor(sy, 1);
  float mx = (oddl ? a_ii : a_il) + rx;
  float my = (oddl ? a_li : a_ll) + ry;
  const bool hi2 = (lane & 2) != 0;
  float s1 = hi2 ? mx : my;
  float r1 = __shfl_xor(s1, 2);
  float v = (hi2 ? my : mx) + r1;
  v += __shfl_xor(v, 4);
  v += __shfl_xor(v, 8);
  v += __shfl_xor(v, 16);
  v += __shfl_xor(v, 32);

  if (lane < 4) {
    const bool badf = (lane & 1) ? bad_in : bad_lb;
    const float s = badf ? v + kNegInf : v;
    const int slot = ((lane & 1) << 1) | ((lane >> 1) & 1);  // il0 ii2 ll1 li3
    sims[1 + slot * KK + k] = s;
  }
}

__global__ void init_kernel(unsigned* stats) {
  if (threadIdx.x == 0) {
    stats[0] = 0u;  // acc count
    stats[1] = 0u;  // worklist count
  }
}

// Fused prep: f16-convert both tables, hash both label tables, init stats.
__global__ __launch_bounds__(256) void prep_kernel(
    const float* __restrict__ ie, const float* __restrict__ ale,
    const float* __restrict__ labels, const float* __restrict__ al,
    ushort* __restrict__ ie_h, ushort* __restrict__ ale_h,
    unsigned long long* __restrict__ h_lab, unsigned long long* __restrict__ h_al,
    unsigned* __restrict__ stats) {
  const int i = blockIdx.x * 256 + threadIdx.x;
  if (i == 0) {
    stats[0] = 0u;
    stats[1] = 0u;
  }
  const int n8_ie = BB * DD / 8;
  if (i < n8_ie) {
    cvt8h(ie, ie_h, i);
  } else {
    cvt8h(ale, ale_h, i - n8_ie);
  }
  if (i < BB) {
    h_lab[i] = hash20(labels + (size_t)i * LLAB);
  } else if (i < BB + NN) {
    h_al[i - BB] = hash20(al + (size_t)(i - BB) * LLAB);
  }
}

// Main pass: one block (4 waves) per row; each wave owns 16 negatives.
// Explicit triple-buffered prefetch: 3 named buffer sets x 2 k-pairs;
// issue set g+2's loads while computing set g (8 vector loads in flight).
#define LOADG(S, g)                                   \
  A0##S = ld_row(ale_h, jls[2 * (g)], lane);          \
  B0##S = ld_row(ie_h, jis[2 * (g)], lane);           \
  A1##S = ld_row(ale_h, jls[2 * (g) + 1], lane);      \
  B1##S = ld_row(ie_h, jis[2 * (g) + 1], lane);       \
  bl0##S = (h_al[jls[2 * (g)]] == hb);                \
  bi0##S = (h_lab[jis[2 * (g)]] == hb);               \
  bl1##S = (h_al[jls[2 * (g) + 1]] == hb);            \
  bi1##S = (h_lab[jis[2 * (g) + 1]] == hb);

#define COMPG(S, g)                                                          \
  compute_k(A0##S, B0##S, bl0##S, bi0##S, qih, qlh, lane, sims,              \
            kbase + 2 * (g));                                                \
  compute_k(A1##S, B1##S, bl1##S, bi1##S, qih, qlh, lane, sims,              \
            kbase + 2 * (g) + 1);

__global__ __launch_bounds__(256, 6) void row_f16_kernel(
    const float* __restrict__ ie, const float* __restrict__ le,
    const ushort* __restrict__ ie_h, const ushort* __restrict__ ale_h,
    const unsigned long long* __restrict__ h_lab,
    const unsigned long long* __restrict__ h_al,
    const int* __restrict__ nin, const int* __restrict__ nlb,
    float* __restrict__ per_ex, int* __restrict__ wl,
    unsigned* __restrict__ stats) {
  const int b = blockIdx.x;
  const int tid = threadIdx.x;
  const int lane = tid & 63;
  const int wave = tid >> 6;

  __shared__ float sims[1 + 4 * KK];
  __shared__ float wred[8];

  const float4* ie4 = (const float4*)(ie + (size_t)b * DD);
  const float4* le4 = (const float4*)(le + (size_t)b * DD);
  float4 qi0 = ie4[2 * lane], qi1 = ie4[2 * lane + 1];
  float4 ql0 = le4[2 * lane], ql1 = le4[2 * lane + 1];

  if (wave == 0) {
    float p = dot4(qi0, ql0) + dot4(qi1, ql1);
    p = waveReduceSum(p);
    if (lane == 0) sims[0] = p;
  }

  uint4 qih, qlh;
  qih.x = pk_h(qi0.x, qi0.y);
  qih.y = pk_h(qi0.z, qi0.w);
  qih.z = pk_h(qi1.x, qi1.y);
  qih.w = pk_h(qi1.z, qi1.w);
  qlh.x = pk_h(ql0.x, ql0.y);
  qlh.y = pk_h(ql0.z, ql0.w);
  qlh.z = pk_h(ql1.x, ql1.y);
  qlh.w = pk_h(ql1.z, ql1.w);

  const unsigned long long hb = h_lab[b];
  const int wuni = __builtin_amdgcn_readfirstlane(wave);
  const int base = b * KK + wuni * 16;
  const int kbase = wuni * 16;

  // All 32 indices upfront (uniform, contiguous -> wide s_loads).
  int jls[16], jis[16];
#pragma unroll
  for (int t = 0; t < 16; ++t) {
    jls[t] = nlb[base + t];
    jis[t] = nin[base + t];
  }

  uint4 A0a, B0a, A1a, B1a, A0b, B0b, A1b, B1b, A0c, B0c, A1c, B1c;
  bool bl0a, bi0a, bl1a, bi1a, bl0b, bi0b, bl1b, bi1b, bl0c, bi0c, bl1c, bi1c;

  LOADG(a, 0)
  LOADG(b, 1)
  LOADG(c, 2) COMPG(a, 0)
  LOADG(a, 3) COMPG(b, 1)
  LOADG(b, 4) COMPG(c, 2)
  LOADG(c, 5) COMPG(a, 3)
  LOADG(a, 6) COMPG(b, 4)
  LOADG(b, 7) COMPG(c, 5)
  COMPG(a, 6)
  COMPG(b, 7)

  __syncthreads();

  const float v = sims[1 + tid];
  const float s0 = sims[0];
  float wmax = waveReduceMax(v);
  if (lane == 0) wred[wave] = wmax;
  __syncthreads();
  float m = fmaxf(fmaxf(wred[0], wred[1]), fmaxf(wred[2], wred[3]));
  m = fmaxf(m, s0);
  const float e = expf(v - m);
  float wsum = waveReduceSum(e);
  if (lane == 0) wred[4 + wave] = wsum;
  __syncthreads();
  if (tid == 0) {
    const float tot = wred[4] + wred[5] + wred[6] + wred[7] + expf(s0 - m);
    const float pe = m + logf(tot) - s0;
    per_ex[b] = pe;
    const float max_il = wred[0];  // wave 0 reduced sims[1..64] = il negatives
    const bool wl_row = (pe < 1.0f) || (fabsf(s0 - max_il) < 0.25f);
    if (wl_row) {
      const unsigned p = atomicAdd(&stats[1], 1u);
      wl[p] = b;
    } else if (s0 >= max_il) {
      atomicAdd(&stats[0], 1u);
    }
  }
}

// Exact f32 row compute (shared by fallback and fixup).
__device__ __forceinline__ void row_f32_body(
    int b, const float* __restrict__ ie, const float* __restrict__ le,
    const float* __restrict__ labels, const float* __restrict__ ale,
    const float* __restrict__ al, const int* __restrict__ nin,
    const int* __restrict__ nlb, float* __restrict__ per_ex,
    unsigned* __restrict__ stats, bool count_acc, float* sims, float* wred) {
  const int tid = threadIdx.x;
  const int lane = tid & 63;
  const int wave = tid >> 6;

  const float4* ie4 = (const float4*)(ie + (size_t)b * DD);
  const float4* le4 = (const float4*)(le + (size_t)b * DD);
  float4 ier0 = ie4[lane], ier1 = ie4[lane + 64];
  float4 ler0 = le4[lane], ler1 = le4[lane + 64];
  float lab = (lane < LLAB) ? labels[(size_t)b * LLAB + lane] : 0.0f;

  if (wave == 0) {
    float p = dot4(ier0, ler0) + dot4(ier1, ler1);
    p = waveReduceSum(p);
    if (lane == 0) sims[0] = p;
  }

#pragma unroll 2
  for (int kk = 0; kk < KK / 4; ++kk) {
    const int k = wave * (KK / 4) + kk;
    const int j_lb = __builtin_amdgcn_readfirstlane(nlb[(size_t)b * KK + k]);
    const int j_in = __builtin_amdgcn_readfirstlane(nin[(size_t)b * KK + k]);

    const float4* rle = (const float4*)(ale + (size_t)j_lb * DD);
    const float4* rie = (const float4*)(ie + (size_t)j_in * DD);
    float4 vle0 = rle[lane], vle1 = rle[lane + 64];
    float4 vie0 = rie[lane], vie1 = rie[lane + 64];

    bool ein = true, elb = true;
    if (lane < LLAB) {
      ein = (labels[(size_t)j_in * LLAB + lane] == lab);
      elb = (al[(size_t)j_lb * LLAB + lane] == lab);
    }
    const bool bad_in = (__ballot(ein) == ~0ull);
    const bool bad_lb = (__ballot(elb) == ~0ull);

    float a_il = dot4(vle0, ier0) + dot4(vle1, ier1);
    float a_ll = dot4(vle0, ler0) + dot4(vle1, ler1);
    float a_ii = dot4(vie0, ier0) + dot4(vie1, ier1);
    float a_li = dot4(vie0, ler0) + dot4(vie1, ler1);

    const bool oddl = (lane & 1) != 0;
    float sx = oddl ? a_il : a_ii;
    float sy = oddl ? a_ll : a_li;
    float rx = __shfl_xor(sx, 1);
    float ry = __shfl_xor(sy, 1);
    float mx = (oddl ? a_ii : a_il) + rx;
    float my = (oddl ? a_li : a_ll) + ry;
    const bool hi2 = (lane & 2) != 0;
    float s1 = hi2 ? mx : my;
    float r1 = __shfl_xor(s1, 2);
    float v = (hi2 ? my : mx) + r1;
    v += __shfl_xor(v, 4);
    v += __shfl_xor(v, 8);
    v += __shfl_xor(v, 16);
    v += __shfl_xor(v, 32);

    if (lane < 4) {
      const bool badf = (lane & 1) ? bad_in : bad_lb;
      const float s = badf ? v + kNegInf : v;
      const int slot = ((lane & 1) << 1) | ((lane >> 1) & 1);
      sims[1 + slot * KK + k] = s;
    }
  }
  __syncthreads();

  const float v = sims[1 + tid];
  const float s0 = sims[0];
  float wmax = waveReduceMax(v);
  if (lane == 0) wred[wave] = wmax;
  __syncthreads();
  float m = fmaxf(fmaxf(wred[0], wred[1]), fmaxf(wred[2], wred[3]));
  m = fmaxf(m, s0);
  const float e = expf(v - m);
  float wsum = waveReduceSum(e);
  if (lane == 0) wred[4 + wave] = wsum;
  __syncthreads();
  if (tid == 0) {
    const float tot = wred[4] + wred[5] + wred[6] + wred[7] + expf(s0 - m);
    per_ex[b] = m + logf(tot) - s0;
    if (count_acc) {
      const float max_il = wred[0];
      if (s0 >= max_il) atomicAdd(&stats[0], 1u);
    }
  }
}

// Fallback: full exact pass (used only if ws too small).
__global__ __launch_bounds__(256) void row_f32_kernel(
    const float* __restrict__ ie, const float* __restrict__ le,
    const float* __restrict__ labels, const float* __restrict__ ale,
    const float* __restrict__ al, const int* __restrict__ nin,
    const int* __restrict__ nlb, float* __restrict__ per_ex,
    unsigned* __restrict__ stats) {
  __shared__ float sims[1 + 4 * KK];
  __shared__ float wred[8];
  row_f32_body(blockIdx.x, ie, le, labels, ale, al, nin, nlb, per_ex, stats,
               true, sims, wred);
}

// Fixup: exact recompute (per_ex AND acc) of worklist rows.
__global__ __launch_bounds__(256) void fixup_kernel(
    const float* __restrict__ ie, const float* __restrict__ le,
    const float* __restrict__ labels, const float* __restrict__ ale,
    const float* __restrict__ al, const int* __restrict__ nin,
    const int* __restrict__ nlb, float* __restrict__ per_ex,
    const int* __restrict__ wl, unsigned* __restrict__ stats) {
  __shared__ float sims[1 + 4 * KK];
  __shared__ float wred[8];
  const int n = (int)stats[1];
  for (int w = blockIdx.x; w < n; w += gridDim.x) {
    row_f32_body(wl[w], ie, le, labels, ale, al, nin, nlb, per_ex, stats,
                 true, sims, wred);
    __syncthreads();
  }
}

__global__ __launch_bounds__(256) void finalize_kernel(
    const float* __restrict__ per_ex, const unsigned* __restrict__ stats,
    float* __restrict__ out) {
  __shared__ float pe_s[BB];  // 16 KB
  __shared__ float wred[8];
  const int tid = threadIdx.x;
  const int lane = tid & 63;
  const int wave = tid >> 6;

  float mn = 1.0e30f;
#pragma unroll 4
  for (int i = tid; i < BB; i += 256) {
    const float v = per_ex[i];
    pe_s[i] = v;
    mn = fminf(mn, v);
  }
  mn = waveReduceMin(mn);
  if (lane == 0) wred[wave] = mn;
  __syncthreads();
  const float minpe = fminf(fminf(wred[0], wred[1]), fminf(wred[2], wred[3]));
  const bool scale_on = (minpe < kLn2);  // max(q) > 0.5
  __syncthreads();

  float sum = 0.0f;
#pragma unroll 4
  for (int i = tid; i < BB; i += 256) {
    const float pe = pe_s[i];
    float s = 1.0f;
    if (scale_on) {
      const float q = expf(-pe);
      const float t = 2.0f * (1.0f - q);
      const float t2 = t * t;
      s = t2 * t2;
    }
    sum += pe * s;
  }
  sum = waveReduceSum(sum);
  if (lane == 0) wred[4 + wave] = sum;
  __syncthreads();
  if (tid == 0) {
    const float tot = wred[4] + wred[5] + wred[6] + wred[7];
    out[0] = tot / (float)BB;
    out[1] = (float)stats[0] / (float)BB;
  }
}

extern "C" void kernel_launch(void* const* d_in, const int* in_sizes, int n_in,
                              void* d_out, int out_size, void* d_ws, size_t ws_size,
                              hipStream_t stream) {
  const float* ie = (const float*)d_in[0];
  const float* le = (const float*)d_in[1];
  const float* labels = (const float*)d_in[2];
  const float* ale = (const float*)d_in[3];
  const float* al = (const float*)d_in[4];
  const int* nin = (const int*)d_in[5];
  const int* nlb = (const int*)d_in[6];
  float* out = (float*)d_out;

  float* per_ex = (float*)d_ws;
  unsigned* stats = (unsigned*)((char*)d_ws + OFF_STATS);
  int* wl = (int*)((char*)d_ws + OFF_WL);

  if (ws_size >= WS_NEED) {
    ushort* ie_h = (ushort*)((char*)d_ws + OFF_IEH);
    ushort* ale_h = (ushort*)((char*)d_ws + OFF_ALEH);
    unsigned long long* h_lab = (unsigned long long*)((char*)d_ws + OFF_HLAB);
    unsigned long long* h_al = (unsigned long long*)((char*)d_ws + OFF_HAL);
    const int prep_blocks = (BB * DD / 8 + NN * DD / 8) / 256;
    hipLaunchKernelGGL(prep_kernel, dim3(prep_blocks), dim3(256), 0, stream,
                       ie, ale, labels, al, ie_h, ale_h, h_lab, h_al, stats);
    hipLaunchKernelGGL(row_f16_kernel, dim3(BB), dim3(256), 0, stream,
                       ie, le, ie_h, ale_h, h_lab, h_al, nin, nlb, per_ex, wl, stats);
    hipLaunchKernelGGL(fixup_kernel, dim3(64), dim3(256), 0, stream,
                       ie, le, labels, ale, al, nin, nlb, per_ex, wl, stats);
  } else {
    hipLaunchKernelGGL(init_kernel, dim3(1), dim3(64), 0, stream, stats);
    hipLaunchKernelGGL(row_f32_kernel, dim3(BB), dim3(256), 0, stream,
                       ie, le, labels, ale, al, nin, nlb, per_ex, stats);
  }
  hipLaunchKernelGGL(finalize_kernel, dim3(1), dim3(256), 0, stream,
                     per_ex, stats, out);
}

// Round 6
// 72.111 us; speedup vs baseline: 1.2963x; 1.2482x over previous
//
#include <hip/hip_runtime.h>
#include <hip/hip_bf16.h>

#define BB 4096
#define DD 512
#define LLAB 20
#define NN 8192
#define KK 64

constexpr float kNegInf = -1.0e9f;
constexpr float kLn2 = 0.69314718055994530942f;
constexpr float kWlPe = 2.5f;   // per_ex worklist band (scale-branch safety)
constexpr float kWlTie = 2.0f;  // accuracy near-tie band

// workspace layout (bytes)
#define OFF_STATS 16384
#define OFF_WL    16640
#define OFF_HLAB  33280                       // 4096*8
#define OFF_HAL   66048                       // 8192*8
#define OFF_SIE   131584                      // 4096*4
#define OFF_SALE  147968                      // 8192*4
#define OFF_IEQ   180736                      // 4096*512 i8
#define OFF_ALEQ  (OFF_IEQ + (size_t)BB * DD) // 8192*512 i8
#define WS_NEED   (OFF_ALEQ + (size_t)NN * DD)

__device__ __forceinline__ float dot4(const float4& a, const float4& b) {
  return a.x * b.x + a.y * b.y + a.z * b.z + a.w * b.w;
}

__device__ __forceinline__ float waveReduceSum(float v) {
#pragma unroll
  for (int s = 1; s < 64; s <<= 1) v += __shfl_xor(v, s);
  return v;
}

__device__ __forceinline__ float waveReduceMax(float v) {
#pragma unroll
  for (int s = 1; s < 64; s <<= 1) v = fmaxf(v, __shfl_xor(v, s));
  return v;
}

__device__ __forceinline__ float waveReduceMin(float v) {
#pragma unroll
  for (int s = 1; s < 64; s <<= 1) v = fminf(v, __shfl_xor(v, s));
  return v;
}

__device__ __forceinline__ unsigned long long hash20(const float* __restrict__ p) {
  unsigned long long h = 1469598103934665603ull;
#pragma unroll
  for (int t = 0; t < LLAB; ++t) {
    h ^= (unsigned long long)__float_as_uint(p[t]);
    h *= 1099511628211ull;
  }
  return h;
}

// i8x4 dot with i32 accumulate (v_dot4_i32_i8).
__device__ __forceinline__ int sdot4i(unsigned a, unsigned b, int acc) {
#if __has_builtin(__builtin_amdgcn_sdot4)
  return __builtin_amdgcn_sdot4((int)a, (int)b, acc, false);
#else
#pragma unroll
  for (int t = 0; t < 4; ++t)
    acc += (int)(signed char)(a >> (8 * t)) * (int)(signed char)(b >> (8 * t));
  return acc;
#endif
}

// pack 4 floats to 4 int8 (RNE, |x*inv| <= 127 by construction).
__device__ __forceinline__ unsigned pk4i8(float a, float b, float c, float d, float inv) {
  const int q0 = (int)rintf(a * inv);
  const int q1 = (int)rintf(b * inv);
  const int q2 = (int)rintf(c * inv);
  const int q3 = (int)rintf(d * inv);
  return (q0 & 255) | ((q1 & 255) << 8) | ((q2 & 255) << 16) | ((q3 & 255) << 24);
}

__device__ __forceinline__ float max8abs(const float4& a, const float4& c) {
  return fmaxf(fmaxf(fmaxf(fabsf(a.x), fabsf(a.y)), fmaxf(fabsf(a.z), fabsf(a.w))),
               fmaxf(fmaxf(fabsf(c.x), fabsf(c.y)), fmaxf(fabsf(c.z), fabsf(c.w))));
}

__global__ void init_kernel(unsigned* stats) {
  if (threadIdx.x == 0) {
    stats[0] = 0u;  // acc count
    stats[1] = 0u;  // worklist count
  }
}

// Prep: per-row absmax-quantize ie (4096 rows) and ale (8192 rows) to int8
// (one wave per row), hash both label tables, init stats.
__global__ __launch_bounds__(256) void prep_kernel(
    const float* __restrict__ ie, const float* __restrict__ ale,
    const float* __restrict__ labels, const float* __restrict__ al,
    char* __restrict__ ie_q, char* __restrict__ ale_q,
    float* __restrict__ s_ie, float* __restrict__ s_ale,
    unsigned long long* __restrict__ h_lab,
    unsigned long long* __restrict__ h_al, unsigned* __restrict__ stats) {
  const int tid = threadIdx.x;
  const int lane = tid & 63;
  const int wave = tid >> 6;
  const int w = blockIdx.x * 4 + wave;  // 0..12287

  const float* src;
  char* dst;
  float* sc;
  int row;
  if (w < BB) {
    src = ie; dst = ie_q; sc = s_ie; row = w;
  } else {
    src = ale; dst = ale_q; sc = s_ale; row = w - BB;
  }

  const float4* r4 = (const float4*)(src + (size_t)row * DD);
  const float4 a = r4[2 * lane], c = r4[2 * lane + 1];
  float mx = waveReduceMax(max8abs(a, c));
  mx = fmaxf(mx, 1e-20f);
  const float inv = 127.0f / mx;
  uint2 o;
  o.x = pk4i8(a.x, a.y, a.z, a.w, inv);
  o.y = pk4i8(c.x, c.y, c.z, c.w, inv);
  ((uint2*)(dst + (size_t)row * DD))[lane] = o;
  if (lane == 0) sc[row] = mx * (1.0f / 127.0f);

  const int g = blockIdx.x * 256 + tid;
  if (g == 0) {
    stats[0] = 0u;
    stats[1] = 0u;
  }
  if (g < BB) h_lab[g] = hash20(labels + (size_t)g * LLAB);
  else if (g < BB + NN) h_al[g - BB] = hash20(al + (size_t)(g - BB) * LLAB);
}

// Main pass: one block (4 waves) per row b; each wave owns 16 negatives.
// int8 gathers (512 B/row), sdot4 dots, exact-int32 butterfly reduction,
// scales applied at the end. sim_pos exact f32.
__global__ __launch_bounds__(256, 8) void row_i8_kernel(
    const float* __restrict__ ie, const float* __restrict__ le,
    const char* __restrict__ ie_q, const char* __restrict__ ale_q,
    const float* __restrict__ s_ie, const float* __restrict__ s_ale,
    const unsigned long long* __restrict__ h_lab,
    const unsigned long long* __restrict__ h_al,
    const int* __restrict__ nin, const int* __restrict__ nlb,
    float* __restrict__ per_ex, int* __restrict__ wl,
    unsigned* __restrict__ stats) {
  const int b = blockIdx.x;
  const int tid = threadIdx.x;
  const int lane = tid & 63;
  const int wave = tid >> 6;

  __shared__ float sims[1 + 4 * KK];
  __shared__ float wred[8];

  // f32 query fragments: elements lane*8 .. lane*8+7.
  const float4* ie4 = (const float4*)(ie + (size_t)b * DD);
  const float4* le4 = (const float4*)(le + (size_t)b * DD);
  const float4 qi0 = ie4[2 * lane], qi1 = ie4[2 * lane + 1];
  const float4 ql0 = le4[2 * lane], ql1 = le4[2 * lane + 1];

  if (wave == 0) {
    float p = dot4(qi0, ql0) + dot4(qi1, ql1);
    p = waveReduceSum(p);
    if (lane == 0) sims[0] = p;
  }

  // In-register query quantization (per-row absmax across the wave).
  float ami = fmaxf(waveReduceMax(max8abs(qi0, qi1)), 1e-20f);
  float aml = fmaxf(waveReduceMax(max8abs(ql0, ql1)), 1e-20f);
  const float inv_i = 127.0f / ami, sq_i = ami * (1.0f / 127.0f);
  const float inv_l = 127.0f / aml, sq_l = aml * (1.0f / 127.0f);
  const unsigned qi8x = pk4i8(qi0.x, qi0.y, qi0.z, qi0.w, inv_i);
  const unsigned qi8y = pk4i8(qi1.x, qi1.y, qi1.z, qi1.w, inv_i);
  const unsigned ql8x = pk4i8(ql0.x, ql0.y, ql0.z, ql0.w, inv_l);
  const unsigned ql8y = pk4i8(ql1.x, ql1.y, ql1.z, ql1.w, inv_l);

  const unsigned long long hb = h_lab[b];
  const int wuni = __builtin_amdgcn_readfirstlane(wave);
  const int base = b * KK + wuni * 16;
  const int kbase = wuni * 16;

#pragma unroll 4
  for (int kk = 0; kk < 16; ++kk) {
    const int jl = nlb[base + kk];  // uniform -> s_load
    const int ji = nin[base + kk];  // uniform -> s_load

    const uint2 A = ((const uint2*)(ale_q + (size_t)jl * DD))[lane];   // 8 i8
    const uint2 Bv = ((const uint2*)(ie_q + (size_t)ji * DD))[lane];   // 8 i8

    const bool bad_lb = (h_al[jl] == hb);
    const bool bad_in = (h_lab[ji] == hb);
    const float srow_a = s_ale[jl];
    const float srow_b = s_ie[ji];

    int d_il = sdot4i(A.x, qi8x, 0);  d_il = sdot4i(A.y, qi8y, d_il);
    int d_ll = sdot4i(A.x, ql8x, 0);  d_ll = sdot4i(A.y, ql8y, d_ll);
    int d_ii = sdot4i(Bv.x, qi8x, 0); d_ii = sdot4i(Bv.y, qi8y, d_ii);
    int d_li = sdot4i(Bv.x, ql8x, 0); d_li = sdot4i(Bv.y, ql8y, d_li);

    // exact int32 component-split butterfly; lane&3: 0->il, 1->ii, 2->ll, 3->li
    const bool oddl = (lane & 1) != 0;
    int sx = oddl ? d_il : d_ii;
    int sy = oddl ? d_ll : d_li;
    int rx = __shfl_xor(sx, 1);
    int ry = __shfl_xor(sy, 1);
    int mxv = (oddl ? d_ii : d_il) + rx;
    int myv = (oddl ? d_li : d_ll) + ry;
    const bool hi2 = (lane & 2) != 0;
    int s1 = hi2 ? mxv : myv;
    int r1 = __shfl_xor(s1, 2);
    int vi = (hi2 ? myv : mxv) + r1;
    vi += __shfl_xor(vi, 4);
    vi += __shfl_xor(vi, 8);
    vi += __shfl_xor(vi, 16);
    vi += __shfl_xor(vi, 32);

    if (lane < 4) {
      const float srow = (lane & 1) ? srow_b : srow_a;
      const float sq = (lane & 2) ? sq_l : sq_i;
      const float v = (float)vi * (srow * sq);
      const bool badf = (lane & 1) ? bad_in : bad_lb;
      const float s = badf ? v + kNegInf : v;
      const int slot = ((lane & 1) << 1) | ((lane >> 1) & 1);  // il0 ii2 ll1 li3
      sims[1 + slot * KK + kbase + kk] = s;
    }
  }
  __syncthreads();

  const float v = sims[1 + tid];
  const float s0 = sims[0];
  float wmax = waveReduceMax(v);
  if (lane == 0) wred[wave] = wmax;
  __syncthreads();
  float m = fmaxf(fmaxf(wred[0], wred[1]), fmaxf(wred[2], wred[3]));
  m = fmaxf(m, s0);
  const float e = expf(v - m);
  float wsum = waveReduceSum(e);
  if (lane == 0) wred[4 + wave] = wsum;
  __syncthreads();
  if (tid == 0) {
    const float tot = wred[4] + wred[5] + wred[6] + wred[7] + expf(s0 - m);
    const float pe = m + logf(tot) - s0;
    per_ex[b] = pe;
    const float max_il = wred[0];  // wave 0 reduced sims[1..64] = il negatives
    const bool wl_row = (pe < kWlPe) || (fabsf(s0 - max_il) < kWlTie);
    if (wl_row) {
      const unsigned p = atomicAdd(&stats[1], 1u);
      wl[p] = b;
    } else if (s0 >= max_il) {
      atomicAdd(&stats[0], 1u);
    }
  }
}

// Exact f32 row compute (shared by fallback and fixup).
__device__ __forceinline__ void row_f32_body(
    int b, const float* __restrict__ ie, const float* __restrict__ le,
    const float* __restrict__ labels, const float* __restrict__ ale,
    const float* __restrict__ al, const int* __restrict__ nin,
    const int* __restrict__ nlb, float* __restrict__ per_ex,
    unsigned* __restrict__ stats, bool count_acc, float* sims, float* wred) {
  const int tid = threadIdx.x;
  const int lane = tid & 63;
  const int wave = tid >> 6;

  const float4* ie4 = (const float4*)(ie + (size_t)b * DD);
  const float4* le4 = (const float4*)(le + (size_t)b * DD);
  float4 ier0 = ie4[lane], ier1 = ie4[lane + 64];
  float4 ler0 = le4[lane], ler1 = le4[lane + 64];
  float lab = (lane < LLAB) ? labels[(size_t)b * LLAB + lane] : 0.0f;

  if (wave == 0) {
    float p = dot4(ier0, ler0) + dot4(ier1, ler1);
    p = waveReduceSum(p);
    if (lane == 0) sims[0] = p;
  }

#pragma unroll 2
  for (int kk = 0; kk < KK / 4; ++kk) {
    const int k = wave * (KK / 4) + kk;
    const int j_lb = __builtin_amdgcn_readfirstlane(nlb[(size_t)b * KK + k]);
    const int j_in = __builtin_amdgcn_readfirstlane(nin[(size_t)b * KK + k]);

    const float4* rle = (const float4*)(ale + (size_t)j_lb * DD);
    const float4* rie = (const float4*)(ie + (size_t)j_in * DD);
    float4 vle0 = rle[lane], vle1 = rle[lane + 64];
    float4 vie0 = rie[lane], vie1 = rie[lane + 64];

    bool ein = true, elb = true;
    if (lane < LLAB) {
      ein = (labels[(size_t)j_in * LLAB + lane] == lab);
      elb = (al[(size_t)j_lb * LLAB + lane] == lab);
    }
    const bool bad_in = (__ballot(ein) == ~0ull);
    const bool bad_lb = (__ballot(elb) == ~0ull);

    float a_il = dot4(vle0, ier0) + dot4(vle1, ier1);
    float a_ll = dot4(vle0, ler0) + dot4(vle1, ler1);
    float a_ii = dot4(vie0, ier0) + dot4(vie1, ier1);
    float a_li = dot4(vie0, ler0) + dot4(vie1, ler1);

    const bool oddl = (lane & 1) != 0;
    float sx = oddl ? a_il : a_ii;
    float sy = oddl ? a_ll : a_li;
    float rx = __shfl_xor(sx, 1);
    float ry = __shfl_xor(sy, 1);
    float mx = (oddl ? a_ii : a_il) + rx;
    float my = (oddl ? a_li : a_ll) + ry;
    const bool hi2 = (lane & 2) != 0;
    float s1 = hi2 ? mx : my;
    float r1 = __shfl_xor(s1, 2);
    float v = (hi2 ? my : mx) + r1;
    v += __shfl_xor(v, 4);
    v += __shfl_xor(v, 8);
    v += __shfl_xor(v, 16);
    v += __shfl_xor(v, 32);

    if (lane < 4) {
      const bool badf = (lane & 1) ? bad_in : bad_lb;
      const float s = badf ? v + kNegInf : v;
      const int slot = ((lane & 1) << 1) | ((lane >> 1) & 1);
      sims[1 + slot * KK + k] = s;
    }
  }
  __syncthreads();

  const float v = sims[1 + tid];
  const float s0 = sims[0];
  float wmax = waveReduceMax(v);
  if (lane == 0) wred[wave] = wmax;
  __syncthreads();
  float m = fmaxf(fmaxf(wred[0], wred[1]), fmaxf(wred[2], wred[3]));
  m = fmaxf(m, s0);
  const float e = expf(v - m);
  float wsum = waveReduceSum(e);
  if (lane == 0) wred[4 + wave] = wsum;
  __syncthreads();
  if (tid == 0) {
    const float tot = wred[4] + wred[5] + wred[6] + wred[7] + expf(s0 - m);
    per_ex[b] = m + logf(tot) - s0;
    if (count_acc) {
      const float max_il = wred[0];
      if (s0 >= max_il) atomicAdd(&stats[0], 1u);
    }
  }
}

// Fallback: full exact pass (used only if ws too small).
__global__ __launch_bounds__(256) void row_f32_kernel(
    const float* __restrict__ ie, const float* __restrict__ le,
    const float* __restrict__ labels, const float* __restrict__ ale,
    const float* __restrict__ al, const int* __restrict__ nin,
    const int* __restrict__ nlb, float* __restrict__ per_ex,
    unsigned* __restrict__ stats) {
  __shared__ float sims[1 + 4 * KK];
  __shared__ float wred[8];
  row_f32_body(blockIdx.x, ie, le, labels, ale, al, nin, nlb, per_ex, stats,
               true, sims, wred);
}

// Fixup: exact recompute (per_ex AND acc) of worklist rows.
__global__ __launch_bounds__(256) void fixup_kernel(
    const float* __restrict__ ie, const float* __restrict__ le,
    const float* __restrict__ labels, const float* __restrict__ ale,
    const float* __restrict__ al, const int* __restrict__ nin,
    const int* __restrict__ nlb, float* __restrict__ per_ex,
    const int* __restrict__ wl, unsigned* __restrict__ stats) {
  __shared__ float sims[1 + 4 * KK];
  __shared__ float wred[8];
  const int n = (int)stats[1];
  for (int w = blockIdx.x; w < n; w += gridDim.x) {
    row_f32_body(wl[w], ie, le, labels, ale, al, nin, nlb, per_ex, stats,
                 true, sims, wred);
    __syncthreads();
  }
}

__global__ __launch_bounds__(256) void finalize_kernel(
    const float* __restrict__ per_ex, const unsigned* __restrict__ stats,
    float* __restrict__ out) {
  __shared__ float pe_s[BB];  // 16 KB
  __shared__ float wred[8];
  const int tid = threadIdx.x;
  const int lane = tid & 63;
  const int wave = tid >> 6;

  float mn = 1.0e30f;
#pragma unroll 4
  for (int i = tid; i < BB; i += 256) {
    const float v = per_ex[i];
    pe_s[i] = v;
    mn = fminf(mn, v);
  }
  mn = waveReduceMin(mn);
  if (lane == 0) wred[wave] = mn;
  __syncthreads();
  const float minpe = fminf(fminf(wred[0], wred[1]), fminf(wred[2], wred[3]));
  const bool scale_on = (minpe < kLn2);  // max(q) > 0.5
  __syncthreads();

  float sum = 0.0f;
#pragma unroll 4
  for (int i = tid; i < BB; i += 256) {
    const float pe = pe_s[i];
    float s = 1.0f;
    if (scale_on) {
      const float q = expf(-pe);
      const float t = 2.0f * (1.0f - q);
      const float t2 = t * t;
      s = t2 * t2;
    }
    sum += pe * s;
  }
  sum = waveReduceSum(sum);
  if (lane == 0) wred[4 + wave] = sum;
  __syncthreads();
  if (tid == 0) {
    const float tot = wred[4] + wred[5] + wred[6] + wred[7];
    out[0] = tot / (float)BB;
    out[1] = (float)stats[0] / (float)BB;
  }
}

extern "C" void kernel_launch(void* const* d_in, const int* in_sizes, int n_in,
                              void* d_out, int out_size, void* d_ws, size_t ws_size,
                              hipStream_t stream) {
  const float* ie = (const float*)d_in[0];
  const float* le = (const float*)d_in[1];
  const float* labels = (const float*)d_in[2];
  const float* ale = (const float*)d_in[3];
  const float* al = (const float*)d_in[4];
  const int* nin = (const int*)d_in[5];
  const int* nlb = (const int*)d_in[6];
  float* out = (float*)d_out;

  float* per_ex = (float*)d_ws;
  unsigned* stats = (unsigned*)((char*)d_ws + OFF_STATS);
  int* wl = (int*)((char*)d_ws + OFF_WL);

  if (ws_size >= WS_NEED) {
    char* ie_q = (char*)d_ws + OFF_IEQ;
    char* ale_q = (char*)d_ws + OFF_ALEQ;
    float* s_ie = (float*)((char*)d_ws + OFF_SIE);
    float* s_ale = (float*)((char*)d_ws + OFF_SALE);
    unsigned long long* h_lab = (unsigned long long*)((char*)d_ws + OFF_HLAB);
    unsigned long long* h_al = (unsigned long long*)((char*)d_ws + OFF_HAL);
    const int prep_blocks = (BB + NN) / 4;  // one wave per quantized row
    hipLaunchKernelGGL(prep_kernel, dim3(prep_blocks), dim3(256), 0, stream,
                       ie, ale, labels, al, ie_q, ale_q, s_ie, s_ale,
                       h_lab, h_al, stats);
    hipLaunchKernelGGL(row_i8_kernel, dim3(BB), dim3(256), 0, stream,
                       ie, le, ie_q, ale_q, s_ie, s_ale, h_lab, h_al,
                       nin, nlb, per_ex, wl, stats);
    hipLaunchKernelGGL(fixup_kernel, dim3(64), dim3(256), 0, stream,
                       ie, le, labels, ale, al, nin, nlb, per_ex, wl, stats);
  } else {
    hipLaunchKernelGGL(init_kernel, dim3(1), dim3(64), 0, stream, stats);
    hipLaunchKernelGGL(row_f32_kernel, dim3(BB), dim3(256), 0, stream,
                       ie, le, labels, ale, al, nin, nlb, per_ex, stats);
  }
  hipLaunchKernelGGL(finalize_kernel, dim3(1), dim3(256), 0, stream,
                     per_ex, stats, out);
}

// Round 7
// 58.210 us; speedup vs baseline: 1.6059x; 1.2388x over previous
//
#include <hip/hip_runtime.h>
#include <hip/hip_bf16.h>

#define BB 4096
#define DD 512
#define LLAB 20
#define NN 8192
#define KK 64

constexpr float kNegInf = -1.0e9f;
constexpr float kLn2 = 0.69314718055994530942f;
constexpr float kWlPe = 2.5f;   // per_ex worklist band (scale-branch safety)
constexpr float kWlTie = 2.0f;  // accuracy near-tie band

// workspace layout (bytes)
#define OFF_STATS 16384
#define OFF_WL    16640
#define OFF_HLAB  33280                       // 4096*8
#define OFF_HAL   66048                       // 8192*8
#define OFF_SIE   131584                      // 4096*4
#define OFF_SALE  147968                      // 8192*4
#define OFF_IEQ   180736                      // 4096*512 i8
#define OFF_ALEQ  (OFF_IEQ + (size_t)BB * DD) // 8192*512 i8
#define WS_NEED   (OFF_ALEQ + (size_t)NN * DD)

__device__ __forceinline__ float dot4(const float4& a, const float4& b) {
  return a.x * b.x + a.y * b.y + a.z * b.z + a.w * b.w;
}

__device__ __forceinline__ float waveReduceSum(float v) {
#pragma unroll
  for (int s = 1; s < 64; s <<= 1) v += __shfl_xor(v, s);
  return v;
}

__device__ __forceinline__ float waveReduceMax(float v) {
#pragma unroll
  for (int s = 1; s < 64; s <<= 1) v = fmaxf(v, __shfl_xor(v, s));
  return v;
}

__device__ __forceinline__ float waveReduceMin(float v) {
#pragma unroll
  for (int s = 1; s < 64; s <<= 1) v = fminf(v, __shfl_xor(v, s));
  return v;
}

__device__ __forceinline__ unsigned long long hash20(const float* __restrict__ p) {
  unsigned long long h = 1469598103934665603ull;
#pragma unroll
  for (int t = 0; t < LLAB; ++t) {
    h ^= (unsigned long long)__float_as_uint(p[t]);
    h *= 1099511628211ull;
  }
  return h;
}

// i8x4 dot with i32 accumulate (v_dot4_i32_i8).
__device__ __forceinline__ int sdot4i(unsigned a, unsigned b, int acc) {
#if __has_builtin(__builtin_amdgcn_sdot4)
  return __builtin_amdgcn_sdot4((int)a, (int)b, acc, false);
#else
#pragma unroll
  for (int t = 0; t < 4; ++t)
    acc += (int)(signed char)(a >> (8 * t)) * (int)(signed char)(b >> (8 * t));
  return acc;
#endif
}

// pack 4 floats to 4 int8 (RNE, |x*inv| <= 127 by construction).
__device__ __forceinline__ unsigned pk4i8(float a, float b, float c, float d, float inv) {
  const int q0 = (int)rintf(a * inv);
  const int q1 = (int)rintf(b * inv);
  const int q2 = (int)rintf(c * inv);
  const int q3 = (int)rintf(d * inv);
  return (q0 & 255) | ((q1 & 255) << 8) | ((q2 & 255) << 16) | ((q3 & 255) << 24);
}

__device__ __forceinline__ float max8abs(const float4& a, const float4& c) {
  return fmaxf(fmaxf(fmaxf(fabsf(a.x), fabsf(a.y)), fmaxf(fabsf(a.z), fabsf(a.w))),
               fmaxf(fmaxf(fabsf(c.x), fabsf(c.y)), fmaxf(fabsf(c.z), fabsf(c.w))));
}

__global__ void init_kernel(unsigned* stats) {
  if (threadIdx.x == 0) {
    stats[0] = 0u;  // acc count
    stats[1] = 0u;  // worklist count
  }
}

// Prep: per-row absmax-quantize ie (4096 rows) and ale (8192 rows) to int8
// (one wave per row), hash both label tables, init stats.
__global__ __launch_bounds__(256) void prep_kernel(
    const float* __restrict__ ie, const float* __restrict__ ale,
    const float* __restrict__ labels, const float* __restrict__ al,
    char* __restrict__ ie_q, char* __restrict__ ale_q,
    float* __restrict__ s_ie, float* __restrict__ s_ale,
    unsigned long long* __restrict__ h_lab,
    unsigned long long* __restrict__ h_al, unsigned* __restrict__ stats) {
  const int tid = threadIdx.x;
  const int lane = tid & 63;
  const int wave = tid >> 6;
  const int w = blockIdx.x * 4 + wave;  // 0..12287

  const float* src;
  char* dst;
  float* sc;
  int row;
  if (w < BB) {
    src = ie; dst = ie_q; sc = s_ie; row = w;
  } else {
    src = ale; dst = ale_q; sc = s_ale; row = w - BB;
  }

  const float4* r4 = (const float4*)(src + (size_t)row * DD);
  const float4 a = r4[2 * lane], c = r4[2 * lane + 1];
  float mx = waveReduceMax(max8abs(a, c));
  mx = fmaxf(mx, 1e-20f);
  const float inv = 127.0f / mx;
  uint2 o;
  o.x = pk4i8(a.x, a.y, a.z, a.w, inv);
  o.y = pk4i8(c.x, c.y, c.z, c.w, inv);
  ((uint2*)(dst + (size_t)row * DD))[lane] = o;
  if (lane == 0) sc[row] = mx * (1.0f / 127.0f);

  const int g = blockIdx.x * 256 + tid;
  if (g == 0) {
    stats[0] = 0u;
    stats[1] = 0u;
  }
  if (g < BB) h_lab[g] = hash20(labels + (size_t)g * LLAB);
  else if (g < BB + NN) h_al[g - BB] = hash20(al + (size_t)(g - BB) * LLAB);
}

// Main pass: one block (4 waves) per row b. Each 4-lane quad owns ONE
// negative k entirely: lane c of the quad holds 128 of the 512 i8 elements
// (interleaved 16B chunks i*64 + c*16), so all 16 row-pair gathers of the
// wave are independent and in flight simultaneously. Cross-lane reduction
// is 2 shfls within the quad (component-split: c0->il c1->ii c2->ll c3->li).
__global__ __launch_bounds__(256, 4) void row_i8_kernel(
    const float* __restrict__ ie, const float* __restrict__ le,
    const char* __restrict__ ie_q, const char* __restrict__ ale_q,
    const float* __restrict__ s_ie, const float* __restrict__ s_ale,
    const unsigned long long* __restrict__ h_lab,
    const unsigned long long* __restrict__ h_al,
    const int* __restrict__ nin, const int* __restrict__ nlb,
    float* __restrict__ per_ex, int* __restrict__ wl,
    unsigned* __restrict__ stats) {
  const int b = blockIdx.x;
  const int tid = threadIdx.x;
  const int lane = tid & 63;
  const int wave = tid >> 6;
  const int c = lane & 3;
  const int g = lane >> 2;

  // Quantized queries, permuted so each lane's 128-element slice is
  // contiguous; slice stride 36 dwords (144B) -> conflict-free + 16B-aligned.
  __shared__ unsigned qs[2][144];
  __shared__ float qsc[2];
  __shared__ float sims[1 + 4 * KK];
  __shared__ float wred[8];

  const int wuni = __builtin_amdgcn_readfirstlane(wave);
  const int k = wuni * 16 + g;

  // Per-quad indices (16 consecutive dwords per wave -> coalesced).
  const int jl = nlb[b * KK + k];
  const int ji = nin[b * KK + k];
  const unsigned long long hb = h_lab[b];
  const bool bad_lb = (h_al[jl] == hb);
  const bool bad_in = (h_lab[ji] == hb);
  const float sA = s_ale[jl];
  const float sB = s_ie[ji];

  // Issue all 16 independent gather-chunk loads upfront.
  const uint4* arow = (const uint4*)(ale_q + (size_t)jl * DD);
  const uint4* brow = (const uint4*)(ie_q + (size_t)ji * DD);
  uint4 Ar[8], Br[8];
#pragma unroll
  for (int i = 0; i < 8; ++i) {
    Ar[i] = arow[i * 4 + c];
    Br[i] = brow[i * 4 + c];
  }

  // Wave 0: sim_pos (exact f32) + query quantization into LDS.
  if (wave == 0) {
    const float4* ie4 = (const float4*)(ie + (size_t)b * DD);
    const float4* le4 = (const float4*)(le + (size_t)b * DD);
    const float4 qi0 = ie4[2 * lane], qi1 = ie4[2 * lane + 1];
    const float4 ql0 = le4[2 * lane], ql1 = le4[2 * lane + 1];
    float p = dot4(qi0, ql0) + dot4(qi1, ql1);
    p = waveReduceSum(p);
    if (lane == 0) sims[0] = p;
    const float ami = fmaxf(waveReduceMax(max8abs(qi0, qi1)), 1e-20f);
    const float aml = fmaxf(waveReduceMax(max8abs(ql0, ql1)), 1e-20f);
    const float inv_i = 127.0f / ami, inv_l = 127.0f / aml;
    if (lane == 0) {
      qsc[0] = ami * (1.0f / 127.0f);
      qsc[1] = aml * (1.0f / 127.0f);
    }
    // lane holds elements [8*lane, 8*lane+8) = chunk ch=lane>>1, dwords (lane&1)*2.
    const int cw = (lane >> 1) & 3, iw = lane >> 3;
    const int woff = cw * 36 + iw * 4 + (lane & 1) * 2;
    qs[0][woff] = pk4i8(qi0.x, qi0.y, qi0.z, qi0.w, inv_i);
    qs[0][woff + 1] = pk4i8(qi1.x, qi1.y, qi1.z, qi1.w, inv_i);
    qs[1][woff] = pk4i8(ql0.x, ql0.y, ql0.z, ql0.w, inv_l);
    qs[1][woff + 1] = pk4i8(ql1.x, ql1.y, ql1.z, ql1.w, inv_l);
  }
  __syncthreads();

  // 128 sdot4 per lane, 4 independent accumulators.
  int il = 0, ll = 0, ii = 0, li = 0;
#pragma unroll
  for (int i = 0; i < 8; ++i) {
    const uint4 qi = *(const uint4*)&qs[0][c * 36 + i * 4];
    const uint4 ql = *(const uint4*)&qs[1][c * 36 + i * 4];
    il = sdot4i(Ar[i].x, qi.x, il); il = sdot4i(Ar[i].y, qi.y, il);
    il = sdot4i(Ar[i].z, qi.z, il); il = sdot4i(Ar[i].w, qi.w, il);
    ll = sdot4i(Ar[i].x, ql.x, ll); ll = sdot4i(Ar[i].y, ql.y, ll);
    ll = sdot4i(Ar[i].z, ql.z, ll); ll = sdot4i(Ar[i].w, ql.w, ll);
    ii = sdot4i(Br[i].x, qi.x, ii); ii = sdot4i(Br[i].y, qi.y, ii);
    ii = sdot4i(Br[i].z, qi.z, ii); ii = sdot4i(Br[i].w, qi.w, ii);
    li = sdot4i(Br[i].x, ql.x, li); li = sdot4i(Br[i].y, ql.y, li);
    li = sdot4i(Br[i].z, ql.z, li); li = sdot4i(Br[i].w, ql.w, li);
  }

  // 2-shfl component-split within the quad.
  const bool odd = (lane & 1) != 0;
  const int x = odd ? il : ii;
  const int y = odd ? ll : li;
  const int rx = __shfl_xor(x, 1);
  const int ry = __shfl_xor(y, 1);
  const int aa = (odd ? ii : il) + rx;
  const int bb = (odd ? li : ll) + ry;
  const bool hi2 = (lane & 2) != 0;
  const int s1 = hi2 ? aa : bb;
  const int r1 = __shfl_xor(s1, 2);
  const int vi = (hi2 ? bb : aa) + r1;

  // lane c: 0->il, 1->ii, 2->ll, 3->li
  const float srow = (c & 1) ? sB : sA;
  const float sq = (c & 2) ? qsc[1] : qsc[0];
  const float v = (float)vi * (srow * sq);
  const bool badf = (c & 1) ? bad_in : bad_lb;
  const float s = badf ? v + kNegInf : v;
  const int slot = ((c & 1) << 1) | (c >> 1);  // il0 ii2 ll1 li3
  sims[1 + slot * KK + k] = s;
  __syncthreads();

  const float vv = sims[1 + tid];
  const float s0 = sims[0];
  float wmax = waveReduceMax(vv);
  if (lane == 0) wred[wave] = wmax;
  __syncthreads();
  float m = fmaxf(fmaxf(wred[0], wred[1]), fmaxf(wred[2], wred[3]));
  m = fmaxf(m, s0);
  const float e = expf(vv - m);
  float wsum = waveReduceSum(e);
  if (lane == 0) wred[4 + wave] = wsum;
  __syncthreads();
  if (tid == 0) {
    const float tot = wred[4] + wred[5] + wred[6] + wred[7] + expf(s0 - m);
    const float pe = m + logf(tot) - s0;
    per_ex[b] = pe;
    const float max_il = wred[0];  // wave 0 reduced sims[1..64] = il negatives
    const bool wl_row = (pe < kWlPe) || (fabsf(s0 - max_il) < kWlTie);
    if (wl_row) {
      const unsigned p = atomicAdd(&stats[1], 1u);
      wl[p] = b;
    } else if (s0 >= max_il) {
      atomicAdd(&stats[0], 1u);
    }
  }
}

// Exact f32 row compute (shared by fallback and fixup).
__device__ __forceinline__ void row_f32_body(
    int b, const float* __restrict__ ie, const float* __restrict__ le,
    const float* __restrict__ labels, const float* __restrict__ ale,
    const float* __restrict__ al, const int* __restrict__ nin,
    const int* __restrict__ nlb, float* __restrict__ per_ex,
    unsigned* __restrict__ stats, bool count_acc, float* sims, float* wred) {
  const int tid = threadIdx.x;
  const int lane = tid & 63;
  const int wave = tid >> 6;

  const float4* ie4 = (const float4*)(ie + (size_t)b * DD);
  const float4* le4 = (const float4*)(le + (size_t)b * DD);
  float4 ier0 = ie4[lane], ier1 = ie4[lane + 64];
  float4 ler0 = le4[lane], ler1 = le4[lane + 64];
  float lab = (lane < LLAB) ? labels[(size_t)b * LLAB + lane] : 0.0f;

  if (wave == 0) {
    float p = dot4(ier0, ler0) + dot4(ier1, ler1);
    p = waveReduceSum(p);
    if (lane == 0) sims[0] = p;
  }

#pragma unroll 2
  for (int kk = 0; kk < KK / 4; ++kk) {
    const int k = wave * (KK / 4) + kk;
    const int j_lb = __builtin_amdgcn_readfirstlane(nlb[(size_t)b * KK + k]);
    const int j_in = __builtin_amdgcn_readfirstlane(nin[(size_t)b * KK + k]);

    const float4* rle = (const float4*)(ale + (size_t)j_lb * DD);
    const float4* rie = (const float4*)(ie + (size_t)j_in * DD);
    float4 vle0 = rle[lane], vle1 = rle[lane + 64];
    float4 vie0 = rie[lane], vie1 = rie[lane + 64];

    bool ein = true, elb = true;
    if (lane < LLAB) {
      ein = (labels[(size_t)j_in * LLAB + lane] == lab);
      elb = (al[(size_t)j_lb * LLAB + lane] == lab);
    }
    const bool bad_in = (__ballot(ein) == ~0ull);
    const bool bad_lb = (__ballot(elb) == ~0ull);

    float a_il = dot4(vle0, ier0) + dot4(vle1, ier1);
    float a_ll = dot4(vle0, ler0) + dot4(vle1, ler1);
    float a_ii = dot4(vie0, ier0) + dot4(vie1, ier1);
    float a_li = dot4(vie0, ler0) + dot4(vie1, ler1);

    const bool oddl = (lane & 1) != 0;
    float sx = oddl ? a_il : a_ii;
    float sy = oddl ? a_ll : a_li;
    float rx = __shfl_xor(sx, 1);
    float ry = __shfl_xor(sy, 1);
    float mx = (oddl ? a_ii : a_il) + rx;
    float my = (oddl ? a_li : a_ll) + ry;
    const bool hi2 = (lane & 2) != 0;
    float s1 = hi2 ? mx : my;
    float r1 = __shfl_xor(s1, 2);
    float v = (hi2 ? my : mx) + r1;
    v += __shfl_xor(v, 4);
    v += __shfl_xor(v, 8);
    v += __shfl_xor(v, 16);
    v += __shfl_xor(v, 32);

    if (lane < 4) {
      const bool badf = (lane & 1) ? bad_in : bad_lb;
      const float s = badf ? v + kNegInf : v;
      const int slot = ((lane & 1) << 1) | ((lane >> 1) & 1);
      sims[1 + slot * KK + k] = s;
    }
  }
  __syncthreads();

  const float v = sims[1 + tid];
  const float s0 = sims[0];
  float wmax = waveReduceMax(v);
  if (lane == 0) wred[wave] = wmax;
  __syncthreads();
  float m = fmaxf(fmaxf(wred[0], wred[1]), fmaxf(wred[2], wred[3]));
  m = fmaxf(m, s0);
  const float e = expf(v - m);
  float wsum = waveReduceSum(e);
  if (lane == 0) wred[4 + wave] = wsum;
  __syncthreads();
  if (tid == 0) {
    const float tot = wred[4] + wred[5] + wred[6] + wred[7] + expf(s0 - m);
    per_ex[b] = m + logf(tot) - s0;
    if (count_acc) {
      const float max_il = wred[0];
      if (s0 >= max_il) atomicAdd(&stats[0], 1u);
    }
  }
}

// Fallback: full exact pass (used only if ws too small).
__global__ __launch_bounds__(256) void row_f32_kernel(
    const float* __restrict__ ie, const float* __restrict__ le,
    const float* __restrict__ labels, const float* __restrict__ ale,
    const float* __restrict__ al, const int* __restrict__ nin,
    const int* __restrict__ nlb, float* __restrict__ per_ex,
    unsigned* __restrict__ stats) {
  __shared__ float sims[1 + 4 * KK];
  __shared__ float wred[8];
  row_f32_body(blockIdx.x, ie, le, labels, ale, al, nin, nlb, per_ex, stats,
               true, sims, wred);
}

// Fixup: exact recompute (per_ex AND acc) of worklist rows.
__global__ __launch_bounds__(256) void fixup_kernel(
    const float* __restrict__ ie, const float* __restrict__ le,
    const float* __restrict__ labels, const float* __restrict__ ale,
    const float* __restrict__ al, const int* __restrict__ nin,
    const int* __restrict__ nlb, float* __restrict__ per_ex,
    const int* __restrict__ wl, unsigned* __restrict__ stats) {
  __shared__ float sims[1 + 4 * KK];
  __shared__ float wred[8];
  const int n = (int)stats[1];
  for (int w = blockIdx.x; w < n; w += gridDim.x) {
    row_f32_body(wl[w], ie, le, labels, ale, al, nin, nlb, per_ex, stats,
                 true, sims, wred);
    __syncthreads();
  }
}

__global__ __launch_bounds__(256) void finalize_kernel(
    const float* __restrict__ per_ex, const unsigned* __restrict__ stats,
    float* __restrict__ out) {
  __shared__ float pe_s[BB];  // 16 KB
  __shared__ float wred[8];
  const int tid = threadIdx.x;
  const int lane = tid & 63;
  const int wave = tid >> 6;

  float mn = 1.0e30f;
#pragma unroll 4
  for (int i = tid; i < BB; i += 256) {
    const float v = per_ex[i];
    pe_s[i] = v;
    mn = fminf(mn, v);
  }
  mn = waveReduceMin(mn);
  if (lane == 0) wred[wave] = mn;
  __syncthreads();
  const float minpe = fminf(fminf(wred[0], wred[1]), fminf(wred[2], wred[3]));
  const bool scale_on = (minpe < kLn2);  // max(q) > 0.5
  __syncthreads();

  float sum = 0.0f;
#pragma unroll 4
  for (int i = tid; i < BB; i += 256) {
    const float pe = pe_s[i];
    float s = 1.0f;
    if (scale_on) {
      const float q = expf(-pe);
      const float t = 2.0f * (1.0f - q);
      const float t2 = t * t;
      s = t2 * t2;
    }
    sum += pe * s;
  }
  sum = waveReduceSum(sum);
  if (lane == 0) wred[4 + wave] = sum;
  __syncthreads();
  if (tid == 0) {
    const float tot = wred[4] + wred[5] + wred[6] + wred[7];
    out[0] = tot / (float)BB;
    out[1] = (float)stats[0] / (float)BB;
  }
}

extern "C" void kernel_launch(void* const* d_in, const int* in_sizes, int n_in,
                              void* d_out, int out_size, void* d_ws, size_t ws_size,
                              hipStream_t stream) {
  const float* ie = (const float*)d_in[0];
  const float* le = (const float*)d_in[1];
  const float* labels = (const float*)d_in[2];
  const float* ale = (const float*)d_in[3];
  const float* al = (const float*)d_in[4];
  const int* nin = (const int*)d_in[5];
  const int* nlb = (const int*)d_in[6];
  float* out = (float*)d_out;

  float* per_ex = (float*)d_ws;
  unsigned* stats = (unsigned*)((char*)d_ws + OFF_STATS);
  int* wl = (int*)((char*)d_ws + OFF_WL);

  if (ws_size >= WS_NEED) {
    char* ie_q = (char*)d_ws + OFF_IEQ;
    char* ale_q = (char*)d_ws + OFF_ALEQ;
    float* s_ie = (float*)((char*)d_ws + OFF_SIE);
    float* s_ale = (float*)((char*)d_ws + OFF_SALE);
    unsigned long long* h_lab = (unsigned long long*)((char*)d_ws + OFF_HLAB);
    unsigned long long* h_al = (unsigned long long*)((char*)d_ws + OFF_HAL);
    const int prep_blocks = (BB + NN) / 4;  // one wave per quantized row
    hipLaunchKernelGGL(prep_kernel, dim3(prep_blocks), dim3(256), 0, stream,
                       ie, ale, labels, al, ie_q, ale_q, s_ie, s_ale,
                       h_lab, h_al, stats);
    hipLaunchKernelGGL(row_i8_kernel, dim3(BB), dim3(256), 0, stream,
                       ie, le, ie_q, ale_q, s_ie, s_ale, h_lab, h_al,
                       nin, nlb, per_ex, wl, stats);
    hipLaunchKernelGGL(fixup_kernel, dim3(64), dim3(256), 0, stream,
                       ie, le, labels, ale, al, nin, nlb, per_ex, wl, stats);
  } else {
    hipLaunchKernelGGL(init_kernel, dim3(1), dim3(64), 0, stream, stats);
    hipLaunchKernelGGL(row_f32_kernel, dim3(BB), dim3(256), 0, stream,
                       ie, le, labels, ale, al, nin, nlb, per_ex, stats);
  }
  hipLaunchKernelGGL(finalize_kernel, dim3(1), dim3(256), 0, stream,
                     per_ex, stats, out);
}

// Round 8
// 53.289 us; speedup vs baseline: 1.7542x; 1.0923x over previous
//
#include <hip/hip_runtime.h>
#include <hip/hip_bf16.h>

#define BB 4096
#define DD 512
#define LLAB 20
#define NN 8192
#define KK 64

constexpr float kNegInf = -1.0e9f;
constexpr float kLn2 = 0.69314718055994530942f;
constexpr float kWlPe = 2.5f;   // per_ex safety band (scale-branch)
constexpr float kWlTie = 2.0f;  // accuracy near-tie band

// workspace layout (bytes, all offsets 256-aligned)
#define OFF_STATS 16384
#define OFF_SP    16640
#define OFF_SIE   33024
#define OFF_SLE   49408
#define OFF_SALE  65792
#define OFF_HLAB  98560
#define OFF_HAL   131328
#define OFF_IEQ   196864
#define OFF_LEQ   2294016
#define OFF_ALEQ  4391168
#define WS_NEED   (OFF_ALEQ + (size_t)NN * DD)

__device__ __forceinline__ float dot4(const float4& a, const float4& b) {
  return a.x * b.x + a.y * b.y + a.z * b.z + a.w * b.w;
}

__device__ __forceinline__ float waveReduceSum(float v) {
#pragma unroll
  for (int s = 1; s < 64; s <<= 1) v += __shfl_xor(v, s);
  return v;
}

__device__ __forceinline__ float waveReduceMax(float v) {
#pragma unroll
  for (int s = 1; s < 64; s <<= 1) v = fmaxf(v, __shfl_xor(v, s));
  return v;
}

__device__ __forceinline__ float waveReduceMin(float v) {
#pragma unroll
  for (int s = 1; s < 64; s <<= 1) v = fminf(v, __shfl_xor(v, s));
  return v;
}

__device__ __forceinline__ unsigned long long hash20(const float* __restrict__ p) {
  unsigned long long h = 1469598103934665603ull;
#pragma unroll
  for (int t = 0; t < LLAB; ++t) {
    h ^= (unsigned long long)__float_as_uint(p[t]);
    h *= 1099511628211ull;
  }
  return h;
}

// i8x4 dot with i32 accumulate (v_dot4_i32_i8).
__device__ __forceinline__ int sdot4i(unsigned a, unsigned b, int acc) {
#if __has_builtin(__builtin_amdgcn_sdot4)
  return __builtin_amdgcn_sdot4((int)a, (int)b, acc, false);
#else
#pragma unroll
  for (int t = 0; t < 4; ++t)
    acc += (int)(signed char)(a >> (8 * t)) * (int)(signed char)(b >> (8 * t));
  return acc;
#endif
}

__device__ __forceinline__ unsigned pk4i8(float a, float b, float c, float d, float inv) {
  const int q0 = (int)rintf(a * inv);
  const int q1 = (int)rintf(b * inv);
  const int q2 = (int)rintf(c * inv);
  const int q3 = (int)rintf(d * inv);
  return (q0 & 255) | ((q1 & 255) << 8) | ((q2 & 255) << 16) | ((q3 & 255) << 24);
}

__device__ __forceinline__ float max8abs(const float4& a, const float4& c) {
  return fmaxf(fmaxf(fmaxf(fabsf(a.x), fabsf(a.y)), fmaxf(fabsf(a.z), fabsf(a.w))),
               fmaxf(fmaxf(fabsf(c.x), fabsf(c.y)), fmaxf(fabsf(c.z), fabsf(c.w))));
}

__global__ void init_kernel(unsigned* stats) {
  if (threadIdx.x == 0) stats[0] = 0u;
}

// Prep (one wave per row):
//  w <  BB       : quantize ie[w] AND le[w], exact sim_pos[w] = <ie_w, le_w>
//  w in [BB,3BB+NN): quantize ale[w-BB]
// Plus: FNV row-hashes of both label tables, stats init.
__global__ __launch_bounds__(256) void prep_kernel(
    const float* __restrict__ ie, const float* __restrict__ le,
    const float* __restrict__ ale, const float* __restrict__ labels,
    const float* __restrict__ al, char* __restrict__ ie_q,
    char* __restrict__ le_q, char* __restrict__ ale_q,
    float* __restrict__ s_ie, float* __restrict__ s_le,
    float* __restrict__ s_ale, float* __restrict__ sp,
    unsigned long long* __restrict__ h_lab,
    unsigned long long* __restrict__ h_al, unsigned* __restrict__ stats) {
  const int tid = threadIdx.x;
  const int lane = tid & 63;
  const int wave = tid >> 6;
  const int w = blockIdx.x * 4 + wave;  // 0 .. BB+NN-1

  if (w < BB) {
    const float4* i4 = (const float4*)(ie + (size_t)w * DD);
    const float4* l4 = (const float4*)(le + (size_t)w * DD);
    const float4 a0 = i4[2 * lane], a1 = i4[2 * lane + 1];
    const float4 b0 = l4[2 * lane], b1 = l4[2 * lane + 1];
    // exact sim_pos
    float p = dot4(a0, b0) + dot4(a1, b1);
    p = waveReduceSum(p);
    // quantize ie row
    float mi = fmaxf(waveReduceMax(max8abs(a0, a1)), 1e-20f);
    const float inv_i = 127.0f / mi;
    uint2 oi;
    oi.x = pk4i8(a0.x, a0.y, a0.z, a0.w, inv_i);
    oi.y = pk4i8(a1.x, a1.y, a1.z, a1.w, inv_i);
    ((uint2*)(ie_q + (size_t)w * DD))[lane] = oi;
    // quantize le row
    float ml = fmaxf(waveReduceMax(max8abs(b0, b1)), 1e-20f);
    const float inv_l = 127.0f / ml;
    uint2 ol;
    ol.x = pk4i8(b0.x, b0.y, b0.z, b0.w, inv_l);
    ol.y = pk4i8(b1.x, b1.y, b1.z, b1.w, inv_l);
    ((uint2*)(le_q + (size_t)w * DD))[lane] = ol;
    if (lane == 0) {
      sp[w] = p;
      s_ie[w] = mi * (1.0f / 127.0f);
      s_le[w] = ml * (1.0f / 127.0f);
    }
  } else {
    const int row = w - BB;
    const float4* r4 = (const float4*)(ale + (size_t)row * DD);
    const float4 a = r4[2 * lane], c = r4[2 * lane + 1];
    float mx = fmaxf(waveReduceMax(max8abs(a, c)), 1e-20f);
    const float inv = 127.0f / mx;
    uint2 o;
    o.x = pk4i8(a.x, a.y, a.z, a.w, inv);
    o.y = pk4i8(c.x, c.y, c.z, c.w, inv);
    ((uint2*)(ale_q + (size_t)row * DD))[lane] = o;
    if (lane == 0) s_ale[row] = mx * (1.0f / 127.0f);
  }

  const int g = blockIdx.x * 256 + tid;
  if (g == 0) stats[0] = 0u;
  if (g < BB) h_lab[g] = hash20(labels + (size_t)g * LLAB);
  else if (g < BB + NN) h_al[g - BB] = hash20(al + (size_t)(g - BB) * LLAB);
}

// Exact f32 row compute (fallback + in-kernel fixup path).
__device__ __forceinline__ void row_f32_body(
    int b, const float* __restrict__ ie, const float* __restrict__ le,
    const float* __restrict__ labels, const float* __restrict__ ale,
    const float* __restrict__ al, const int* __restrict__ nin,
    const int* __restrict__ nlb, float* __restrict__ per_ex,
    unsigned* __restrict__ stats, bool count_acc, float* sims, float* wred) {
  const int tid = threadIdx.x;
  const int lane = tid & 63;
  const int wave = tid >> 6;

  const float4* ie4 = (const float4*)(ie + (size_t)b * DD);
  const float4* le4 = (const float4*)(le + (size_t)b * DD);
  float4 ier0 = ie4[lane], ier1 = ie4[lane + 64];
  float4 ler0 = le4[lane], ler1 = le4[lane + 64];
  float lab = (lane < LLAB) ? labels[(size_t)b * LLAB + lane] : 0.0f;

  if (wave == 0) {
    float p = dot4(ier0, ler0) + dot4(ier1, ler1);
    p = waveReduceSum(p);
    if (lane == 0) sims[0] = p;
  }

#pragma unroll 2
  for (int kk = 0; kk < KK / 4; ++kk) {
    const int k = wave * (KK / 4) + kk;
    const int j_lb = __builtin_amdgcn_readfirstlane(nlb[(size_t)b * KK + k]);
    const int j_in = __builtin_amdgcn_readfirstlane(nin[(size_t)b * KK + k]);

    const float4* rle = (const float4*)(ale + (size_t)j_lb * DD);
    const float4* rie = (const float4*)(ie + (size_t)j_in * DD);
    float4 vle0 = rle[lane], vle1 = rle[lane + 64];
    float4 vie0 = rie[lane], vie1 = rie[lane + 64];

    bool ein = true, elb = true;
    if (lane < LLAB) {
      ein = (labels[(size_t)j_in * LLAB + lane] == lab);
      elb = (al[(size_t)j_lb * LLAB + lane] == lab);
    }
    const bool bad_in = (__ballot(ein) == ~0ull);
    const bool bad_lb = (__ballot(elb) == ~0ull);

    float a_il = dot4(vle0, ier0) + dot4(vle1, ier1);
    float a_ll = dot4(vle0, ler0) + dot4(vle1, ler1);
    float a_ii = dot4(vie0, ier0) + dot4(vie1, ier1);
    float a_li = dot4(vie0, ler0) + dot4(vie1, ler1);

    const bool oddl = (lane & 1) != 0;
    float sx = oddl ? a_il : a_ii;
    float sy = oddl ? a_ll : a_li;
    float rx = __shfl_xor(sx, 1);
    float ry = __shfl_xor(sy, 1);
    float mx = (oddl ? a_ii : a_il) + rx;
    float my = (oddl ? a_li : a_ll) + ry;
    const bool hi2 = (lane & 2) != 0;
    float s1 = hi2 ? mx : my;
    float r1 = __shfl_xor(s1, 2);
    float v = (hi2 ? my : mx) + r1;
    v += __shfl_xor(v, 4);
    v += __shfl_xor(v, 8);
    v += __shfl_xor(v, 16);
    v += __shfl_xor(v, 32);

    if (lane < 4) {
      const bool badf = (lane & 1) ? bad_in : bad_lb;
      const float s = badf ? v + kNegInf : v;
      const int slot = ((lane & 1) << 1) | ((lane >> 1) & 1);
      sims[1 + slot * KK + k] = s;
    }
  }
  __syncthreads();

  const float v = sims[1 + tid];
  const float s0 = sims[0];
  float wmax = waveReduceMax(v);
  if (lane == 0) wred[wave] = wmax;
  __syncthreads();
  float m = fmaxf(fmaxf(wred[0], wred[1]), fmaxf(wred[2], wred[3]));
  m = fmaxf(m, s0);
  const float e = expf(v - m);
  float wsum = waveReduceSum(e);
  if (lane == 0) wred[4 + wave] = wsum;
  __syncthreads();
  if (tid == 0) {
    const float tot = wred[4] + wred[5] + wred[6] + wred[7] + expf(s0 - m);
    per_ex[b] = m + logf(tot) - s0;
    if (count_acc) {
      const float max_il = wred[0];
      if (s0 >= max_il) atomicAdd(&stats[0], 1u);
    }
  }
}

// Main pass: one block per row b; each 4-lane quad owns one negative k.
// All tables (queries included) are int8; self-fixup for band rows.
__global__ __launch_bounds__(256, 4) void row_i8_kernel(
    const float* __restrict__ ie, const float* __restrict__ le,
    const float* __restrict__ labels, const float* __restrict__ ale,
    const float* __restrict__ al, const char* __restrict__ ie_q,
    const char* __restrict__ le_q, const char* __restrict__ ale_q,
    const float* __restrict__ s_ie, const float* __restrict__ s_le,
    const float* __restrict__ s_ale, const float* __restrict__ sp,
    const unsigned long long* __restrict__ h_lab,
    const unsigned long long* __restrict__ h_al,
    const int* __restrict__ nin, const int* __restrict__ nlb,
    float* __restrict__ per_ex, unsigned* __restrict__ stats) {
  const int b = blockIdx.x;
  const int tid = threadIdx.x;
  const int lane = tid & 63;
  const int wave = tid >> 6;
  const int c = lane & 3;
  const int g = lane >> 2;

  __shared__ uint4 qls4[64];          // qi8 (32) + ql8 (32), 1 KB
  __shared__ float simsX[1 + 4 * KK]; // exact-path only
  __shared__ float wred[12];
  __shared__ int do_fix;

  const int wuni = __builtin_amdgcn_readfirstlane(wave);
  const int k = wuni * 16 + g;

  const int jl = nlb[b * KK + k];
  const int ji = nin[b * KK + k];
  const unsigned long long hb = h_lab[b];
  const bool bad_lb = (h_al[jl] == hb);
  const bool bad_in = (h_lab[ji] == hb);
  const float sA = s_ale[jl];
  const float sB = s_ie[ji];

  // Issue all 16 independent gather-chunk loads upfront.
  const uint4* arow = (const uint4*)(ale_q + (size_t)jl * DD);
  const uint4* brow = (const uint4*)(ie_q + (size_t)ji * DD);
  uint4 Ar[8], Br[8];
#pragma unroll
  for (int i = 0; i < 8; ++i) {
    Ar[i] = arow[i * 4 + c];
    Br[i] = brow[i * 4 + c];
  }

  // Stage the two 512B quantized query rows to LDS (wave 0).
  if (wave == 0) {
    if (lane < 32) qls4[lane] = ((const uint4*)(ie_q + (size_t)b * DD))[lane];
    else qls4[lane] = ((const uint4*)(le_q + (size_t)b * DD))[lane - 32];
  }
  __syncthreads();

  // 128 sdot4 per lane, 4 independent accumulators.
  int il = 0, ll = 0, ii = 0, li = 0;
#pragma unroll
  for (int i = 0; i < 8; ++i) {
    const uint4 qi = qls4[i * 4 + c];
    const uint4 ql = qls4[32 + i * 4 + c];
    il = sdot4i(Ar[i].x, qi.x, il); il = sdot4i(Ar[i].y, qi.y, il);
    il = sdot4i(Ar[i].z, qi.z, il); il = sdot4i(Ar[i].w, qi.w, il);
    ll = sdot4i(Ar[i].x, ql.x, ll); ll = sdot4i(Ar[i].y, ql.y, ll);
    ll = sdot4i(Ar[i].z, ql.z, ll); ll = sdot4i(Ar[i].w, ql.w, ll);
    ii = sdot4i(Br[i].x, qi.x, ii); ii = sdot4i(Br[i].y, qi.y, ii);
    ii = sdot4i(Br[i].z, qi.z, ii); ii = sdot4i(Br[i].w, qi.w, ii);
    li = sdot4i(Br[i].x, ql.x, li); li = sdot4i(Br[i].y, ql.y, li);
    li = sdot4i(Br[i].z, ql.z, li); li = sdot4i(Br[i].w, ql.w, li);
  }

  // 2-shfl component-split within the quad; lane c: 0->il 1->ii 2->ll 3->li
  const bool odd = (lane & 1) != 0;
  const int x = odd ? il : ii;
  const int y = odd ? ll : li;
  const int rx = __shfl_xor(x, 1);
  const int ry = __shfl_xor(y, 1);
  const int aa = (odd ? ii : il) + rx;
  const int bb2 = (odd ? li : ll) + ry;
  const bool hi2 = (lane & 2) != 0;
  const int s1 = hi2 ? aa : bb2;
  const int r1 = __shfl_xor(s1, 2);
  const int vi = (hi2 ? bb2 : aa) + r1;

  const float srow = (c & 1) ? sB : sA;
  const float sq = (c & 2) ? s_le[b] : s_ie[b];
  const float v = (float)vi * (srow * sq);
  const bool badf = (c & 1) ? bad_in : bad_lb;
  const float s = badf ? v + kNegInf : v;

  const float s0 = sp[b];

  // Block LSE directly from lane-resident sims (no sims array round-trip).
  float m_w = waveReduceMax(s);
  float mil_w = waveReduceMax((c == 0) ? s : -3.0e38f);
  if (lane == 0) {
    wred[wave] = m_w;
    wred[4 + wave] = mil_w;
  }
  __syncthreads();
  float m = fmaxf(fmaxf(fmaxf(wred[0], wred[1]), fmaxf(wred[2], wred[3])), s0);
  const float e = expf(s - m);
  float sum_w = waveReduceSum(e);
  if (lane == 0) wred[8 + wave] = sum_w;
  __syncthreads();
  if (tid == 0) {
    const float tot = wred[8] + wred[9] + wred[10] + wred[11] + expf(s0 - m);
    const float pe = m + logf(tot) - s0;
    per_ex[b] = pe;
    const float max_il = fmaxf(fmaxf(wred[4], wred[5]), fmaxf(wred[6], wred[7]));
    const bool wl_row = (pe < kWlPe) || (fabsf(s0 - max_il) < kWlTie);
    do_fix = wl_row ? 1 : 0;
    if (!wl_row && s0 >= max_il) atomicAdd(&stats[0], 1u);
  }
  __syncthreads();

  // Band rows: exact f32 recompute (per_ex + acc) within this block.
  if (do_fix) {
    row_f32_body(b, ie, le, labels, ale, al, nin, nlb, per_ex, stats,
                 true, simsX, wred);
  }
}

// Fallback: full exact pass (used only if ws too small).
__global__ __launch_bounds__(256) void row_f32_kernel(
    const float* __restrict__ ie, const float* __restrict__ le,
    const float* __restrict__ labels, const float* __restrict__ ale,
    const float* __restrict__ al, const int* __restrict__ nin,
    const int* __restrict__ nlb, float* __restrict__ per_ex,
    unsigned* __restrict__ stats) {
  __shared__ float sims[1 + 4 * KK];
  __shared__ float wred[8];
  row_f32_body(blockIdx.x, ie, le, labels, ale, al, nin, nlb, per_ex, stats,
               true, sims, wred);
}

__global__ __launch_bounds__(256) void finalize_kernel(
    const float* __restrict__ per_ex, const unsigned* __restrict__ stats,
    float* __restrict__ out) {
  __shared__ float pe_s[BB];  // 16 KB
  __shared__ float wred[8];
  const int tid = threadIdx.x;
  const int lane = tid & 63;
  const int wave = tid >> 6;

  float mn = 1.0e30f;
#pragma unroll 4
  for (int i = tid; i < BB; i += 256) {
    const float v = per_ex[i];
    pe_s[i] = v;
    mn = fminf(mn, v);
  }
  mn = waveReduceMin(mn);
  if (lane == 0) wred[wave] = mn;
  __syncthreads();
  const float minpe = fminf(fminf(wred[0], wred[1]), fminf(wred[2], wred[3]));
  const bool scale_on = (minpe < kLn2);  // max(q) > 0.5
  __syncthreads();

  float sum = 0.0f;
#pragma unroll 4
  for (int i = tid; i < BB; i += 256) {
    const float pe = pe_s[i];
    float s = 1.0f;
    if (scale_on) {
      const float q = expf(-pe);
      const float t = 2.0f * (1.0f - q);
      const float t2 = t * t;
      s = t2 * t2;
    }
    sum += pe * s;
  }
  sum = waveReduceSum(sum);
  if (lane == 0) wred[4 + wave] = sum;
  __syncthreads();
  if (tid == 0) {
    const float tot = wred[4] + wred[5] + wred[6] + wred[7];
    out[0] = tot / (float)BB;
    out[1] = (float)stats[0] / (float)BB;
  }
}

extern "C" void kernel_launch(void* const* d_in, const int* in_sizes, int n_in,
                              void* d_out, int out_size, void* d_ws, size_t ws_size,
                              hipStream_t stream) {
  const float* ie = (const float*)d_in[0];
  const float* le = (const float*)d_in[1];
  const float* labels = (const float*)d_in[2];
  const float* ale = (const float*)d_in[3];
  const float* al = (const float*)d_in[4];
  const int* nin = (const int*)d_in[5];
  const int* nlb = (const int*)d_in[6];
  float* out = (float*)d_out;

  float* per_ex = (float*)d_ws;
  unsigned* stats = (unsigned*)((char*)d_ws + OFF_STATS);

  if (ws_size >= WS_NEED) {
    char* ie_q = (char*)d_ws + OFF_IEQ;
    char* le_q = (char*)d_ws + OFF_LEQ;
    char* ale_q = (char*)d_ws + OFF_ALEQ;
    float* s_ie = (float*)((char*)d_ws + OFF_SIE);
    float* s_le = (float*)((char*)d_ws + OFF_SLE);
    float* s_ale = (float*)((char*)d_ws + OFF_SALE);
    float* sp = (float*)((char*)d_ws + OFF_SP);
    unsigned long long* h_lab = (unsigned long long*)((char*)d_ws + OFF_HLAB);
    unsigned long long* h_al = (unsigned long long*)((char*)d_ws + OFF_HAL);
    const int prep_blocks = (BB + NN) / 4;  // one wave per row
    hipLaunchKernelGGL(prep_kernel, dim3(prep_blocks), dim3(256), 0, stream,
                       ie, le, ale, labels, al, ie_q, le_q, ale_q,
                       s_ie, s_le, s_ale, sp, h_lab, h_al, stats);
    hipLaunchKernelGGL(row_i8_kernel, dim3(BB), dim3(256), 0, stream,
                       ie, le, labels, ale, al, ie_q, le_q, ale_q,
                       s_ie, s_le, s_ale, sp, h_lab, h_al, nin, nlb,
                       per_ex, stats);
  } else {
    hipLaunchKernelGGL(init_kernel, dim3(1), dim3(64), 0, stream, stats);
    hipLaunchKernelGGL(row_f32_kernel, dim3(BB), dim3(256), 0, stream,
                       ie, le, labels, ale, al, nin, nlb, per_ex, stats);
  }
  hipLaunchKernelGGL(finalize_kernel, dim3(1), dim3(256), 0, stream,
                     per_ex, stats, out);
}